// Round 3
// baseline (588.430 us; speedup 1.0000x reference)
//
#include <hip/hip_runtime.h>
#include <hip/hip_bf16.h>
#include <stdint.h>

#define B_ 2
#define T_ 2048
#define C_ 1024
#define H_ 16
#define D_ 64
#define F_ 4096
#define M_ (B_*T_)

typedef unsigned short ushort_t;
typedef __attribute__((ext_vector_type(8))) short short8;
typedef __attribute__((ext_vector_type(4))) float f32x4;

__device__ __forceinline__ float bf2f(ushort_t u) {
    union { unsigned u; float f; } c; c.u = ((unsigned)u) << 16; return c.f;
}
__device__ __forceinline__ ushort_t f2bf(float f) {
    union { float f; unsigned u; } c; c.f = f;
    unsigned u = c.u;
    unsigned r = (u + 0x7FFFu + ((u >> 16) & 1u)) >> 16;
    return (ushort_t)r;
}

// ---------------------------------------------------------------------------
// Transpose + cast: out_bf16[c][r] = in_f32[r][c]
// ---------------------------------------------------------------------------
__global__ void transpose_cast_k(const float* __restrict__ in, ushort_t* __restrict__ out,
                                 int R, int C) {
    __shared__ ushort_t tile[32][33];
    int tx = threadIdx.x, ty = threadIdx.y;
    int x = blockIdx.x * 32 + tx;
    int y0 = blockIdx.y * 32;
#pragma unroll
    for (int i = 0; i < 32; i += 8)
        tile[ty + i][tx] = f2bf(in[(size_t)(y0 + ty + i) * C + x]);
    __syncthreads();
    int x2 = y0 + tx;
    int y2 = blockIdx.x * 32;
#pragma unroll
    for (int i = 0; i < 32; i += 8)
        out[(size_t)(y2 + ty + i) * R + x2] = tile[tx][ty + i];
}

// ---------------------------------------------------------------------------
// LayerNorm: fp32 input row of 1024, fp32 scale/shift, bf16 output.
// 256 threads x 4 elems.
// ---------------------------------------------------------------------------
__global__ __launch_bounds__(256) void ln_kernel(const float* __restrict__ xin,
                                                 const float* __restrict__ scale_p,
                                                 const float* __restrict__ shift_p,
                                                 ushort_t* __restrict__ out) {
    int row = blockIdx.x, t = threadIdx.x;
    int wv = t >> 6, lane = t & 63;
    const float* xr = xin + (size_t)row * 1024 + t * 4;
    float4 v = *(const float4*)xr;
    float f[4] = {v.x, v.y, v.z, v.w};
    float s = f[0] + f[1] + f[2] + f[3];
    float q = f[0]*f[0] + f[1]*f[1] + f[2]*f[2] + f[3]*f[3];
#pragma unroll
    for (int off = 1; off < 64; off <<= 1) {
        s += __shfl_xor(s, off, 64);
        q += __shfl_xor(q, off, 64);
    }
    __shared__ float sh_s[4], sh_q[4];
    if (lane == 0) { sh_s[wv] = s; sh_q[wv] = q; }
    __syncthreads();
    float S = sh_s[0] + sh_s[1] + sh_s[2] + sh_s[3];
    float Q = sh_q[0] + sh_q[1] + sh_q[2] + sh_q[3];
    float mean = S * (1.0f / 1024.0f);
    float var = Q * (1.0f / 1024.0f) - mean * mean;
    float rstd = rsqrtf(var + 1e-5f);
    float4 scv = *(const float4*)(scale_p + t * 4);
    float4 shv = *(const float4*)(shift_p + t * 4);
    ushort4 o;
    o.x = f2bf((f[0] - mean) * rstd * scv.x + shv.x);
    o.y = f2bf((f[1] - mean) * rstd * scv.y + shv.y);
    o.z = f2bf((f[2] - mean) * rstd * scv.z + shv.z);
    o.w = f2bf((f[3] - mean) * rstd * scv.w + shv.w);
    *(ushort4*)(out + (size_t)row * 1024 + t * 4) = o;
}

// ---------------------------------------------------------------------------
// GEMM: C[M,N] = A[M,K](bf16) @ Bt[N,K](bf16)^T + bias(f32).
// 128x128 tile, BK=32, 4 waves 2x2. Register staging.
// EPI: 0 = bf16 out; 1 = +f32 residual, f32 out; 2 = gelu, bf16 out.
// ---------------------------------------------------------------------------
template <int EPI>
__global__ __launch_bounds__(256) void gemm_bt(const ushort_t* __restrict__ A,
                                               const ushort_t* __restrict__ Bt,
                                               const float* __restrict__ bias,
                                               const float* __restrict__ res,
                                               void* __restrict__ out,
                                               int M, int N, int K) {
    __shared__ ushort_t As[128 * 32];
    __shared__ ushort_t Bs[128 * 32];
    const int t = threadIdx.x;
    const int wv = t >> 6, lane = t & 63, lo = lane & 15, hi = lane >> 4;
    const int wr = wv >> 1, wc = wv & 1;
    const int mb = blockIdx.y, nb = blockIdx.x;

    f32x4 acc[4][4];
#pragma unroll
    for (int i = 0; i < 4; ++i)
#pragma unroll
        for (int j = 0; j < 4; ++j) acc[i][j] = (f32x4){0.f, 0.f, 0.f, 0.f};

    const int row0 = t >> 2, kc0 = t & 3;

    for (int k0 = 0; k0 < K; k0 += 32) {
        short8 av0 = *(const short8*)(A + (size_t)(mb * 128 + row0) * K + k0 + kc0 * 8);
        short8 av1 = *(const short8*)(A + (size_t)(mb * 128 + 64 + row0) * K + k0 + kc0 * 8);
        short8 bv0 = *(const short8*)(Bt + (size_t)(nb * 128 + row0) * K + k0 + kc0 * 8);
        short8 bv1 = *(const short8*)(Bt + (size_t)(nb * 128 + 64 + row0) * K + k0 + kc0 * 8);
        *(short8*)(As + row0 * 32 + kc0 * 8) = av0;
        *(short8*)(As + (64 + row0) * 32 + kc0 * 8) = av1;
        *(short8*)(Bs + row0 * 32 + kc0 * 8) = bv0;
        *(short8*)(Bs + (64 + row0) * 32 + kc0 * 8) = bv1;
        __syncthreads();

        short8 af[4], bfr[4];
#pragma unroll
        for (int mi = 0; mi < 4; ++mi)
            af[mi] = *(const short8*)(As + (wr * 64 + mi * 16 + lo) * 32 + hi * 8);
#pragma unroll
        for (int ni = 0; ni < 4; ++ni)
            bfr[ni] = *(const short8*)(Bs + (wc * 64 + ni * 16 + lo) * 32 + hi * 8);
#pragma unroll
        for (int mi = 0; mi < 4; ++mi)
#pragma unroll
            for (int ni = 0; ni < 4; ++ni)
                acc[mi][ni] = __builtin_amdgcn_mfma_f32_16x16x32_bf16(
                    af[mi], bfr[ni], acc[mi][ni], 0, 0, 0);
        __syncthreads();
    }

#pragma unroll
    for (int ni = 0; ni < 4; ++ni) {
        int n = nb * 128 + wc * 64 + ni * 16 + lo;
        float bn = bias[n];
#pragma unroll
        for (int mi = 0; mi < 4; ++mi) {
#pragma unroll
            for (int r = 0; r < 4; ++r) {
                int m = mb * 128 + wr * 64 + mi * 16 + 4 * hi + r;
                size_t idx = (size_t)m * N + n;
                float v = acc[mi][ni][r] + bn;
                if (EPI == 0) {
                    ((ushort_t*)out)[idx] = f2bf(v);
                } else if (EPI == 1) {
                    ((float*)out)[idx] = v + res[idx];
                } else {
                    v = 0.5f * v * (1.0f + erff(v * 0.70710678118654752f));
                    ((ushort_t*)out)[idx] = f2bf(v);
                }
            }
        }
    }
}

// ---------------------------------------------------------------------------
// Causal flash attention (bf16 q/k/v/ctx). One block per (64 q-rows, b*h).
// Wave w owns q rows q0+16w..+15. K tile & V^T tile in LDS;
// P: C-layout -> LDS -> A-layout.
// ---------------------------------------------------------------------------
__global__ __launch_bounds__(256) void attn_kernel(const ushort_t* __restrict__ q,
                                                   const ushort_t* __restrict__ k,
                                                   const ushort_t* __restrict__ v,
                                                   ushort_t* __restrict__ ctx) {
    __shared__ ushort_t Ks[64 * 80];
    __shared__ ushort_t VTs[64 * 80];
    __shared__ ushort_t Ps[4][16 * 88];

    const int t = threadIdx.x;
    const int wv = t >> 6, lane = t & 63, lo = lane & 15, hi = lane >> 4;
    const int qb = blockIdx.x, bh = blockIdx.y;
    const int b = bh >> 4, h = bh & 15;
    const int q0 = qb * 64;
    const size_t headoff = (size_t)h * 64;
    const size_t rowbase = (size_t)b * T_ * 1024;

    const ushort_t* qptr = q + rowbase + (size_t)(q0 + wv * 16 + lo) * 1024 + headoff;
    short8 qf0 = *(const short8*)(qptr + hi * 8);
    short8 qf1 = *(const short8*)(qptr + 32 + hi * 8);

    float m_r[4], l_r[4];
    f32x4 o_acc[4];
#pragma unroll
    for (int r = 0; r < 4; ++r) { m_r[r] = -1e30f; l_r[r] = 0.f; }
#pragma unroll
    for (int dt = 0; dt < 4; ++dt) o_acc[dt] = (f32x4){0.f, 0.f, 0.f, 0.f};

    const int ntiles = qb + 1;
    for (int kt = 0; kt < ntiles; ++kt) {
        const int k0 = kt * 64;
#pragma unroll
        for (int i = 0; i < 2; ++i) {
            int c = i * 256 + t;
            int key = c >> 3, d8 = (c & 7) * 8;
            const ushort_t* gk = k + rowbase + (size_t)(k0 + key) * 1024 + headoff + d8;
            short8 kv8 = *(const short8*)gk;
            *(short8*)(Ks + key * 80 + d8) = kv8;
            const ushort_t* gv = v + rowbase + (size_t)(k0 + key) * 1024 + headoff + d8;
            short8 vv = *(const short8*)gv;
#pragma unroll
            for (int j = 0; j < 8; ++j)
                VTs[(d8 + j) * 80 + key] = (ushort_t)vv[j];
        }
        __syncthreads();

        const int cmax = (kt == qb) ? wv : 3;
        f32x4 sacc[4];
#pragma unroll
        for (int kt16 = 0; kt16 < 4; ++kt16) {
            if (kt16 <= cmax) {
                short8 kf0 = *(const short8*)(Ks + (kt16 * 16 + lo) * 80 + hi * 8);
                short8 kf1 = *(const short8*)(Ks + (kt16 * 16 + lo) * 80 + 32 + hi * 8);
                f32x4 z = (f32x4){0.f, 0.f, 0.f, 0.f};
                z = __builtin_amdgcn_mfma_f32_16x16x32_bf16(qf0, kf0, z, 0, 0, 0);
                z = __builtin_amdgcn_mfma_f32_16x16x32_bf16(qf1, kf1, z, 0, 0, 0);
#pragma unroll
                for (int r = 0; r < 4; ++r) sacc[kt16][r] = z[r] * 0.125f;
            } else {
                sacc[kt16] = (f32x4){-1e30f, -1e30f, -1e30f, -1e30f};
            }
        }
        if (kt == qb) {
            int key = k0 + wv * 16 + lo;
#pragma unroll
            for (int r = 0; r < 4; ++r) {
                int qrow = q0 + wv * 16 + 4 * hi + r;
                if (key > qrow) sacc[wv][r] = -1e30f;
            }
        }

        ushort_t* Pw = Ps[wv];
#pragma unroll
        for (int r = 0; r < 4; ++r) {
            float mx = fmaxf(fmaxf(sacc[0][r], sacc[1][r]), fmaxf(sacc[2][r], sacc[3][r]));
#pragma unroll
            for (int off = 1; off < 16; off <<= 1) mx = fmaxf(mx, __shfl_xor(mx, off, 64));
            float mnew = fmaxf(m_r[r], mx);
            float alpha = __expf(m_r[r] - mnew);
            m_r[r] = mnew;
            float rs = 0.f;
#pragma unroll
            for (int kt16 = 0; kt16 < 4; ++kt16) {
                float p = __expf(sacc[kt16][r] - mnew);
                rs += p;
                Pw[(4 * hi + r) * 88 + kt16 * 16 + lo] = f2bf(p);
            }
#pragma unroll
            for (int off = 1; off < 16; off <<= 1) rs += __shfl_xor(rs, off, 64);
            l_r[r] = l_r[r] * alpha + rs;
#pragma unroll
            for (int dt = 0; dt < 4; ++dt) o_acc[dt][r] *= alpha;
        }
        __syncthreads();  // order P writes before fragment reads

        short8 pf0 = *(const short8*)(Pw + lo * 88 + hi * 8);
        short8 pf1 = *(const short8*)(Pw + lo * 88 + 32 + hi * 8);
#pragma unroll
        for (int dt = 0; dt < 4; ++dt) {
            short8 vf0 = *(const short8*)(VTs + (dt * 16 + lo) * 80 + hi * 8);
            short8 vf1 = *(const short8*)(VTs + (dt * 16 + lo) * 80 + 32 + hi * 8);
            o_acc[dt] = __builtin_amdgcn_mfma_f32_16x16x32_bf16(pf0, vf0, o_acc[dt], 0, 0, 0);
            o_acc[dt] = __builtin_amdgcn_mfma_f32_16x16x32_bf16(pf1, vf1, o_acc[dt], 0, 0, 0);
        }
        __syncthreads();
    }

#pragma unroll
    for (int r = 0; r < 4; ++r) {
        float inv = 1.0f / l_r[r];
        size_t row = rowbase + (size_t)(q0 + wv * 16 + 4 * hi + r) * 1024 + headoff;
#pragma unroll
        for (int dt = 0; dt < 4; ++dt)
            ctx[row + dt * 16 + lo] = f2bf(o_acc[dt][r] * inv);
    }
}

// ---------------------------------------------------------------------------
extern "C" void kernel_launch(void* const* d_in, const int* in_sizes, int n_in,
                              void* d_out, int out_size, void* d_ws, size_t ws_size,
                              hipStream_t stream) {
    (void)in_sizes; (void)n_in; (void)out_size; (void)ws_size;
    const float* x    = (const float*)d_in[0];
    const float* Wq   = (const float*)d_in[1];
    const float* bq   = (const float*)d_in[2];
    const float* Wk   = (const float*)d_in[3];
    const float* bk   = (const float*)d_in[4];
    const float* Wv   = (const float*)d_in[5];
    const float* bv   = (const float*)d_in[6];
    const float* Wo   = (const float*)d_in[7];
    const float* bo   = (const float*)d_in[8];
    const float* W1   = (const float*)d_in[9];
    const float* b1   = (const float*)d_in[10];
    const float* W2   = (const float*)d_in[11];
    const float* b2   = (const float*)d_in[12];
    const float* ln1s = (const float*)d_in[13];
    const float* ln1b = (const float*)d_in[14];
    const float* ln2s = (const float*)d_in[15];
    const float* ln2b = (const float*)d_in[16];

    char* ws = (char*)d_ws;
    const size_t MB = 1024 * 1024;
    ushort_t* wtq  = (ushort_t*)(ws + 0 * MB);   // 2MB (1024x1024 bf16)
    ushort_t* wtk  = (ushort_t*)(ws + 2 * MB);
    ushort_t* wtv  = (ushort_t*)(ws + 4 * MB);
    ushort_t* wto  = (ushort_t*)(ws + 6 * MB);
    ushort_t* wt1  = (ushort_t*)(ws + 8 * MB);   // 8MB (4096x1024)
    ushort_t* wt2  = (ushort_t*)(ws + 16 * MB);  // 8MB (1024x4096)
    ushort_t* hbuf = (ushort_t*)(ws + 24 * MB);  // 8MB, LN1 out then LN2 out
    ushort_t* qb_  = (ushort_t*)(ws + 32 * MB);  // 8MB
    ushort_t* kb_  = (ushort_t*)(ws + 40 * MB);  // 8MB
    ushort_t* vb_  = (ushort_t*)(ws + 48 * MB);  // 8MB
    ushort_t* ctx  = (ushort_t*)(ws + 56 * MB);  // 8MB
    ushort_t* hid  = (ushort_t*)(ws + 32 * MB);  // 32MB, reuses q/k/v/ctx region
    float*    x1   = (float*)(ws + 64 * MB);     // 16MB fp32

    dim3 tb(32, 8);
    transpose_cast_k<<<dim3(32, 32), tb, 0, stream>>>(Wq, wtq, 1024, 1024);
    transpose_cast_k<<<dim3(32, 32), tb, 0, stream>>>(Wk, wtk, 1024, 1024);
    transpose_cast_k<<<dim3(32, 32), tb, 0, stream>>>(Wv, wtv, 1024, 1024);
    transpose_cast_k<<<dim3(32, 32), tb, 0, stream>>>(Wo, wto, 1024, 1024);
    transpose_cast_k<<<dim3(128, 32), tb, 0, stream>>>(W1, wt1, 1024, 4096);
    transpose_cast_k<<<dim3(32, 128), tb, 0, stream>>>(W2, wt2, 4096, 1024);

    ln_kernel<<<4096, 256, 0, stream>>>(x, ln1s, ln1b, hbuf);

    gemm_bt<0><<<dim3(8, 32), 256, 0, stream>>>(hbuf, wtq, bq, nullptr, qb_, 4096, 1024, 1024);
    gemm_bt<0><<<dim3(8, 32), 256, 0, stream>>>(hbuf, wtk, bk, nullptr, kb_, 4096, 1024, 1024);
    gemm_bt<0><<<dim3(8, 32), 256, 0, stream>>>(hbuf, wtv, bv, nullptr, vb_, 4096, 1024, 1024);

    attn_kernel<<<dim3(32, 32), 256, 0, stream>>>(qb_, kb_, vb_, ctx);

    gemm_bt<1><<<dim3(8, 32), 256, 0, stream>>>(ctx, wto, bo, x, x1, 4096, 1024, 1024);

    ln_kernel<<<4096, 256, 0, stream>>>(x1, ln2s, ln2b, hbuf);

    gemm_bt<2><<<dim3(32, 32), 256, 0, stream>>>(hbuf, wt1, b1, nullptr, hid, 4096, 4096, 1024);

    gemm_bt<1><<<dim3(8, 32), 256, 0, stream>>>(hid, wt2, b2, x1, (float*)d_out, 4096, 1024, 4096);
}

// Round 4
// 487.906 us; speedup vs baseline: 1.2060x; 1.2060x over previous
//
#include <hip/hip_runtime.h>
#include <hip/hip_bf16.h>
#include <stdint.h>

#define B_ 2
#define T_ 2048
#define C_ 1024
#define H_ 16
#define D_ 64
#define F_ 4096
#define M_ (B_*T_)

typedef unsigned short ushort_t;
typedef __attribute__((ext_vector_type(8))) short short8;
typedef __attribute__((ext_vector_type(4))) float f32x4;

__device__ __forceinline__ float bf2f(ushort_t u) {
    union { unsigned u; float f; } c; c.u = ((unsigned)u) << 16; return c.f;
}
__device__ __forceinline__ ushort_t f2bf(float f) {
    union { float f; unsigned u; } c; c.f = f;
    unsigned u = c.u;
    unsigned r = (u + 0x7FFFu + ((u >> 16) & 1u)) >> 16;
    return (ushort_t)r;
}

// async global->LDS, 16B per lane. LDS dest = wave-uniform base + lane*16.
__device__ __forceinline__ void async16(void* lds, const void* g) {
    __builtin_amdgcn_global_load_lds(
        (const __attribute__((address_space(1))) unsigned int*)(uintptr_t)g,
        (__attribute__((address_space(3))) unsigned int*)(uintptr_t)lds,
        16, 0, 0);
}

// ---------------------------------------------------------------------------
// Transpose + cast: out_bf16[c][r] = in_f32[r][c]
// ---------------------------------------------------------------------------
__global__ void transpose_cast_k(const float* __restrict__ in, ushort_t* __restrict__ out,
                                 int R, int C) {
    __shared__ ushort_t tile[32][33];
    int tx = threadIdx.x, ty = threadIdx.y;
    int x = blockIdx.x * 32 + tx;
    int y0 = blockIdx.y * 32;
#pragma unroll
    for (int i = 0; i < 32; i += 8)
        tile[ty + i][tx] = f2bf(in[(size_t)(y0 + ty + i) * C + x]);
    __syncthreads();
    int x2 = y0 + tx;
    int y2 = blockIdx.x * 32;
#pragma unroll
    for (int i = 0; i < 32; i += 8)
        out[(size_t)(y2 + ty + i) * R + x2] = tile[tx][ty + i];
}

// bf16 full transpose: out[c][r] = in[r][c]
__global__ void transpose_bf_k(const ushort_t* __restrict__ in, ushort_t* __restrict__ out,
                               int R, int C) {
    __shared__ ushort_t tile[32][33];
    int tx = threadIdx.x, ty = threadIdx.y;
    int x = blockIdx.x * 32 + tx;
    int y0 = blockIdx.y * 32;
#pragma unroll
    for (int i = 0; i < 32; i += 8)
        tile[ty + i][tx] = in[(size_t)(y0 + ty + i) * C + x];
    __syncthreads();
    int x2 = y0 + tx;
    int y2 = blockIdx.x * 32;
#pragma unroll
    for (int i = 0; i < 32; i += 8)
        out[(size_t)(y2 + ty + i) * R + x2] = tile[tx][ty + i];
}

// ---------------------------------------------------------------------------
// LayerNorm: fp32 input row of 1024, fp32 scale/shift, bf16 output.
// ---------------------------------------------------------------------------
__global__ __launch_bounds__(256) void ln_kernel(const float* __restrict__ xin,
                                                 const float* __restrict__ scale_p,
                                                 const float* __restrict__ shift_p,
                                                 ushort_t* __restrict__ out) {
    int row = blockIdx.x, t = threadIdx.x;
    int wv = t >> 6, lane = t & 63;
    const float* xr = xin + (size_t)row * 1024 + t * 4;
    float4 v = *(const float4*)xr;
    float f[4] = {v.x, v.y, v.z, v.w};
    float s = f[0] + f[1] + f[2] + f[3];
    float q = f[0]*f[0] + f[1]*f[1] + f[2]*f[2] + f[3]*f[3];
#pragma unroll
    for (int off = 1; off < 64; off <<= 1) {
        s += __shfl_xor(s, off, 64);
        q += __shfl_xor(q, off, 64);
    }
    __shared__ float sh_s[4], sh_q[4];
    if (lane == 0) { sh_s[wv] = s; sh_q[wv] = q; }
    __syncthreads();
    float S = sh_s[0] + sh_s[1] + sh_s[2] + sh_s[3];
    float Q = sh_q[0] + sh_q[1] + sh_q[2] + sh_q[3];
    float mean = S * (1.0f / 1024.0f);
    float var = Q * (1.0f / 1024.0f) - mean * mean;
    float rstd = rsqrtf(var + 1e-5f);
    float4 scv = *(const float4*)(scale_p + t * 4);
    float4 shv = *(const float4*)(shift_p + t * 4);
    ushort4 o;
    o.x = f2bf((f[0] - mean) * rstd * scv.x + shv.x);
    o.y = f2bf((f[1] - mean) * rstd * scv.y + shv.y);
    o.z = f2bf((f[2] - mean) * rstd * scv.z + shv.z);
    o.w = f2bf((f[3] - mean) * rstd * scv.w + shv.w);
    *(ushort4*)(out + (size_t)row * 1024 + t * 4) = o;
}

// ---------------------------------------------------------------------------
// GEMM (m97 structure, async global->LDS staging):
// C[M,N] = A[M,K](bf16) @ Bt[N,K](bf16)^T + bias(f32)
// Tile (32*MT) x 128, BK=32, 4 waves 2x2; wave does MT x 4 16x16 subtiles.
// EPI: 1 = +f32 residual, f32 out (stride N)
//      2 = gelu, bf16 out (stride N)
//      3 = QKV split: 3 outputs bf16, col stride 1024, seg = n>>10
// ---------------------------------------------------------------------------
template <int MT, int EPI>
__global__ __launch_bounds__(256) void gemm_bt(const ushort_t* __restrict__ A,
                                               const ushort_t* __restrict__ Bt,
                                               const float* __restrict__ b0,
                                               const float* __restrict__ b1,
                                               const float* __restrict__ b2,
                                               const float* __restrict__ res,
                                               void* __restrict__ out0,
                                               void* __restrict__ out1,
                                               void* __restrict__ out2,
                                               int M, int N, int K) {
    __shared__ ushort_t As[32 * MT * 32];
    __shared__ ushort_t Bs[128 * 32];
    const int t = threadIdx.x;
    const int wv = t >> 6, lane = t & 63, lo = lane & 15, hi = lane >> 4;
    const int wr = wv >> 1, wc = wv & 1;
    const int mb = blockIdx.y, nb = blockIdx.x;

    f32x4 acc[MT][4];
#pragma unroll
    for (int i = 0; i < MT; ++i)
#pragma unroll
        for (int j = 0; j < 4; ++j) acc[i][j] = (f32x4){0.f, 0.f, 0.f, 0.f};

    for (int k0 = 0; k0 < K; k0 += 32) {
        // A tile: 32*MT rows x 32 cols -> 128*MT chunks of 16B
#pragma unroll
        for (int i = 0; i < MT / 2; ++i) {
            int c = i * 256 + t;
            int row = c >> 2, kc = c & 3;
            async16((char*)As + (size_t)(i * 256 + wv * 64) * 16,
                    A + (size_t)(mb * 32 * MT + row) * K + k0 + kc * 8);
        }
        // B tile: 128 rows x 32 cols -> 512 chunks
#pragma unroll
        for (int i = 0; i < 2; ++i) {
            int c = i * 256 + t;
            int row = c >> 2, kc = c & 3;
            async16((char*)Bs + (size_t)(i * 256 + wv * 64) * 16,
                    Bt + (size_t)(nb * 128 + row) * K + k0 + kc * 8);
        }
        __syncthreads();

        short8 af[MT], bfr[4];
#pragma unroll
        for (int mi = 0; mi < MT; ++mi)
            af[mi] = *(const short8*)(As + (wr * 16 * MT + mi * 16 + lo) * 32 + hi * 8);
#pragma unroll
        for (int ni = 0; ni < 4; ++ni)
            bfr[ni] = *(const short8*)(Bs + (wc * 64 + ni * 16 + lo) * 32 + hi * 8);
#pragma unroll
        for (int mi = 0; mi < MT; ++mi)
#pragma unroll
            for (int ni = 0; ni < 4; ++ni)
                acc[mi][ni] = __builtin_amdgcn_mfma_f32_16x16x32_bf16(
                    af[mi], bfr[ni], acc[mi][ni], 0, 0, 0);
        __syncthreads();
    }

#pragma unroll
    for (int ni = 0; ni < 4; ++ni) {
        int n = nb * 128 + wc * 64 + ni * 16 + lo;
        float bn;
        ushort_t* obf = nullptr;
        int coln = n;
        if (EPI == 3) {
            int seg = n >> 10; coln = n & 1023;
            bn = (seg == 0 ? b0 : seg == 1 ? b1 : b2)[coln];
            obf = (ushort_t*)(seg == 0 ? out0 : seg == 1 ? out1 : out2);
        } else {
            bn = b0[n];
        }
#pragma unroll
        for (int mi = 0; mi < MT; ++mi) {
#pragma unroll
            for (int r = 0; r < 4; ++r) {
                int m = mb * 32 * MT + wr * 16 * MT + mi * 16 + 4 * hi + r;
                float v = acc[mi][ni][r] + bn;
                if (EPI == 1) {
                    size_t idx = (size_t)m * N + n;
                    ((float*)out0)[idx] = v + res[idx];
                } else if (EPI == 2) {
                    v = 0.5f * v * (1.0f + erff(v * 0.70710678118654752f));
                    ((ushort_t*)out0)[(size_t)m * N + n] = f2bf(v);
                } else {
                    obf[(size_t)m * 1024 + coln] = f2bf(v);
                }
            }
        }
    }
}

// ---------------------------------------------------------------------------
// Causal flash attention. One block per (64 q-rows, b*h); qb reversed so
// heavy blocks dispatch first. K and pre-transposed V staged via async16,
// XOR-swizzled columns (read-side per-lane XOR) to break bank conflicts.
// vt layout: [c=h*64+d][b*2048+t]  (full transpose of v buffer)
// ---------------------------------------------------------------------------
__global__ __launch_bounds__(256) void attn_kernel(const ushort_t* __restrict__ q,
                                                   const ushort_t* __restrict__ k,
                                                   const ushort_t* __restrict__ vt,
                                                   ushort_t* __restrict__ ctx) {
    __shared__ ushort_t Ks[64 * 64];    // [key][d], 8 chunks/row, col-swizzled
    __shared__ ushort_t VTs[64 * 64];   // [d][key], col-swizzled
    __shared__ ushort_t Ps[4][16 * 88]; // per-wave P [q][key], pad 88

    const int t = threadIdx.x;
    const int wv = t >> 6, lane = t & 63, lo = lane & 15, hi = lane >> 4;
    const int qb = (int)gridDim.x - 1 - (int)blockIdx.x;
    const int bh = blockIdx.y, b = bh >> 4, h = bh & 15;
    const int q0 = qb * 64;
    const size_t headoff = (size_t)h * 64;
    const size_t rowbase = (size_t)b * T_ * 1024;
    const ushort_t* vbase = vt + headoff * (size_t)M_ + (size_t)b * T_;

    const ushort_t* qptr = q + rowbase + (size_t)(q0 + wv * 16 + lo) * 1024 + headoff;
    short8 qf0 = *(const short8*)(qptr + hi * 8);
    short8 qf1 = *(const short8*)(qptr + 32 + hi * 8);

    float m_r[4], l_r[4];
    f32x4 o_acc[4];
#pragma unroll
    for (int r = 0; r < 4; ++r) { m_r[r] = -1e30f; l_r[r] = 0.f; }
#pragma unroll
    for (int dt = 0; dt < 4; ++dt) o_acc[dt] = (f32x4){0.f, 0.f, 0.f, 0.f};

    for (int kt = 0; kt <= qb; ++kt) {
        const int k0 = kt * 64;
        // stage K tile and V^T tile: 512 chunks each, col-chunk XOR row&7 swizzle
#pragma unroll
        for (int i = 0; i < 2; ++i) {
            int c = i * 256 + t;
            int row = c >> 3, c8 = c & 7;
            int g = c8 ^ (row & 7);
            async16((char*)Ks + (size_t)(i * 256 + wv * 64) * 16,
                    k + rowbase + (size_t)(k0 + row) * 1024 + headoff + g * 8);
            async16((char*)VTs + (size_t)(i * 256 + wv * 64) * 16,
                    vbase + (size_t)row * M_ + k0 + g * 8);
        }
        __syncthreads();

        const int cmax = (kt == qb) ? wv : 3;
        f32x4 sacc[4];
#pragma unroll
        for (int kt16 = 0; kt16 < 4; ++kt16) {
            if (kt16 <= cmax) {
                int row = kt16 * 16 + lo, sw = row & 7;
                short8 kf0 = *(const short8*)(Ks + row * 64 + (hi ^ sw) * 8);
                short8 kf1 = *(const short8*)(Ks + row * 64 + ((4 + hi) ^ sw) * 8);
                f32x4 z = (f32x4){0.f, 0.f, 0.f, 0.f};
                z = __builtin_amdgcn_mfma_f32_16x16x32_bf16(qf0, kf0, z, 0, 0, 0);
                z = __builtin_amdgcn_mfma_f32_16x16x32_bf16(qf1, kf1, z, 0, 0, 0);
#pragma unroll
                for (int r = 0; r < 4; ++r) sacc[kt16][r] = z[r] * 0.125f;
            } else {
                sacc[kt16] = (f32x4){-1e30f, -1e30f, -1e30f, -1e30f};
            }
        }
        if (kt == qb) {
            int key = k0 + wv * 16 + lo;
#pragma unroll
            for (int r = 0; r < 4; ++r) {
                int qrow = q0 + wv * 16 + 4 * hi + r;
                if (key > qrow) sacc[wv][r] = -1e30f;
            }
        }

        ushort_t* Pw = Ps[wv];
#pragma unroll
        for (int r = 0; r < 4; ++r) {
            float mx = fmaxf(fmaxf(sacc[0][r], sacc[1][r]), fmaxf(sacc[2][r], sacc[3][r]));
#pragma unroll
            for (int off = 1; off < 16; off <<= 1) mx = fmaxf(mx, __shfl_xor(mx, off, 64));
            float mnew = fmaxf(m_r[r], mx);
            float alpha = __expf(m_r[r] - mnew);
            m_r[r] = mnew;
            float rs = 0.f;
#pragma unroll
            for (int kt16 = 0; kt16 < 4; ++kt16) {
                float p = __expf(sacc[kt16][r] - mnew);
                rs += p;
                Pw[(4 * hi + r) * 88 + kt16 * 16 + lo] = f2bf(p);
            }
#pragma unroll
            for (int off = 1; off < 16; off <<= 1) rs += __shfl_xor(rs, off, 64);
            l_r[r] = l_r[r] * alpha + rs;
#pragma unroll
            for (int dt = 0; dt < 4; ++dt) o_acc[dt][r] *= alpha;
        }
        __syncthreads();  // order P writes before fragment reads

        short8 pf0 = *(const short8*)(Pw + lo * 88 + hi * 8);
        short8 pf1 = *(const short8*)(Pw + lo * 88 + 32 + hi * 8);
#pragma unroll
        for (int dt = 0; dt < 4; ++dt) {
            int row = dt * 16 + lo, sw = row & 7;
            short8 vf0 = *(const short8*)(VTs + row * 64 + (hi ^ sw) * 8);
            short8 vf1 = *(const short8*)(VTs + row * 64 + ((4 + hi) ^ sw) * 8);
            o_acc[dt] = __builtin_amdgcn_mfma_f32_16x16x32_bf16(pf0, vf0, o_acc[dt], 0, 0, 0);
            o_acc[dt] = __builtin_amdgcn_mfma_f32_16x16x32_bf16(pf1, vf1, o_acc[dt], 0, 0, 0);
        }
        __syncthreads();
    }

#pragma unroll
    for (int r = 0; r < 4; ++r) {
        float inv = 1.0f / l_r[r];
        size_t row = rowbase + (size_t)(q0 + wv * 16 + 4 * hi + r) * 1024 + headoff;
#pragma unroll
        for (int dt = 0; dt < 4; ++dt)
            ctx[row + dt * 16 + lo] = f2bf(o_acc[dt][r] * inv);
    }
}

// ---------------------------------------------------------------------------
extern "C" void kernel_launch(void* const* d_in, const int* in_sizes, int n_in,
                              void* d_out, int out_size, void* d_ws, size_t ws_size,
                              hipStream_t stream) {
    (void)in_sizes; (void)n_in; (void)out_size; (void)ws_size;
    const float* x    = (const float*)d_in[0];
    const float* Wq   = (const float*)d_in[1];
    const float* bq   = (const float*)d_in[2];
    const float* Wk   = (const float*)d_in[3];
    const float* bk   = (const float*)d_in[4];
    const float* Wv   = (const float*)d_in[5];
    const float* bv   = (const float*)d_in[6];
    const float* Wo   = (const float*)d_in[7];
    const float* bo   = (const float*)d_in[8];
    const float* W1   = (const float*)d_in[9];
    const float* b1   = (const float*)d_in[10];
    const float* W2   = (const float*)d_in[11];
    const float* b2   = (const float*)d_in[12];
    const float* ln1s = (const float*)d_in[13];
    const float* ln1b = (const float*)d_in[14];
    const float* ln2s = (const float*)d_in[15];
    const float* ln2b = (const float*)d_in[16];

    char* ws = (char*)d_ws;
    const size_t MB = 1024 * 1024;
    ushort_t* wqkv = (ushort_t*)(ws + 0 * MB);   // 6MB: wtq|wtk|wtv contiguous [3072][1024]
    ushort_t* wtq  = (ushort_t*)(ws + 0 * MB);
    ushort_t* wtk  = (ushort_t*)(ws + 2 * MB);
    ushort_t* wtv  = (ushort_t*)(ws + 4 * MB);
    ushort_t* wto  = (ushort_t*)(ws + 6 * MB);
    ushort_t* wt1  = (ushort_t*)(ws + 8 * MB);   // 8MB (4096x1024)
    ushort_t* wt2  = (ushort_t*)(ws + 16 * MB);  // 8MB (1024x4096)
    ushort_t* hbuf = (ushort_t*)(ws + 24 * MB);  // 8MB, LN1 out then LN2 out
    ushort_t* qb_  = (ushort_t*)(ws + 32 * MB);  // 8MB
    ushort_t* kb_  = (ushort_t*)(ws + 40 * MB);  // 8MB
    ushort_t* vb_  = (ushort_t*)(ws + 48 * MB);  // 8MB
    ushort_t* ctx  = (ushort_t*)(ws + 56 * MB);  // 8MB
    ushort_t* hid  = (ushort_t*)(ws + 32 * MB);  // 32MB, reuses qkv/ctx region post-attn
    float*    x1   = (float*)(ws + 64 * MB);     // 16MB fp32 (written after attn)
    ushort_t* vtb  = (ushort_t*)(ws + 64 * MB);  // 8MB [1024][4096], dead once Wo writes x1

    dim3 tb(32, 8);
    transpose_cast_k<<<dim3(32, 32), tb, 0, stream>>>(Wq, wtq, 1024, 1024);
    transpose_cast_k<<<dim3(32, 32), tb, 0, stream>>>(Wk, wtk, 1024, 1024);
    transpose_cast_k<<<dim3(32, 32), tb, 0, stream>>>(Wv, wtv, 1024, 1024);
    transpose_cast_k<<<dim3(32, 32), tb, 0, stream>>>(Wo, wto, 1024, 1024);
    transpose_cast_k<<<dim3(128, 32), tb, 0, stream>>>(W1, wt1, 1024, 4096);
    transpose_cast_k<<<dim3(32, 128), tb, 0, stream>>>(W2, wt2, 4096, 1024);

    ln_kernel<<<4096, 256, 0, stream>>>(x, ln1s, ln1b, hbuf);

    // fused QKV: [4096][1024] @ [3072][1024]^T -> q,k,v buffers
    gemm_bt<4, 3><<<dim3(24, 32), 256, 0, stream>>>(hbuf, wqkv, bq, bk, bv, nullptr,
                                                    qb_, kb_, vb_, 4096, 3072, 1024);

    // v -> v^T [1024][4096]
    transpose_bf_k<<<dim3(32, 128), tb, 0, stream>>>(vb_, vtb, 4096, 1024);

    attn_kernel<<<dim3(32, 32), 256, 0, stream>>>(qb_, kb_, vtb, ctx);

    // x1 = ctx @ Wo + bo + x   (f32 out)
    gemm_bt<2, 1><<<dim3(8, 64), 256, 0, stream>>>(ctx, wto, bo, nullptr, nullptr, x,
                                                   x1, nullptr, nullptr, 4096, 1024, 1024);

    ln_kernel<<<4096, 256, 0, stream>>>(x1, ln2s, ln2b, hbuf);

    // hid = gelu(h @ W1 + b1)
    gemm_bt<4, 2><<<dim3(32, 32), 256, 0, stream>>>(hbuf, wt1, b1, nullptr, nullptr, nullptr,
                                                    hid, nullptr, nullptr, 4096, 4096, 1024);

    // out = hid @ W2 + b2 + x1  (f32 out)
    gemm_bt<2, 1><<<dim3(8, 64), 256, 0, stream>>>(hid, wt2, b2, nullptr, nullptr, x1,
                                                   (float*)d_out, nullptr, nullptr, 4096, 1024, 4096);
}

// Round 6
// 456.895 us; speedup vs baseline: 1.2879x; 1.0679x over previous
//
#include <hip/hip_runtime.h>
#include <hip/hip_bf16.h>
#include <stdint.h>

#define B_ 2
#define T_ 2048
#define C_ 1024
#define H_ 16
#define D_ 64
#define F_ 4096
#define M_ (B_*T_)

typedef unsigned short ushort_t;
typedef __attribute__((ext_vector_type(8))) short short8;
typedef __attribute__((ext_vector_type(4))) float f32x4;

__device__ __forceinline__ float bf2f(ushort_t u) {
    union { unsigned u; float f; } c; c.u = ((unsigned)u) << 16; return c.f;
}
__device__ __forceinline__ ushort_t f2bf(float f) {
    union { float f; unsigned u; } c; c.f = f;
    unsigned u = c.u;
    unsigned r = (u + 0x7FFFu + ((u >> 16) & 1u)) >> 16;
    return (ushort_t)r;
}

__device__ __forceinline__ float fexp2(float x) { return __builtin_amdgcn_exp2f(x); }

// async global->LDS, 16B per lane. LDS dest = wave-uniform base + lane*16.
__device__ __forceinline__ void async16(void* lds, const void* g) {
    __builtin_amdgcn_global_load_lds(
        (const __attribute__((address_space(1))) unsigned int*)(uintptr_t)g,
        (__attribute__((address_space(3))) unsigned int*)(uintptr_t)lds,
        16, 0, 0);
}

// ---------------------------------------------------------------------------
// Transpose + cast: out_bf16[c][r] = in_f32[r][c]
// ---------------------------------------------------------------------------
__global__ void transpose_cast_k(const float* __restrict__ in, ushort_t* __restrict__ out,
                                 int R, int C) {
    __shared__ ushort_t tile[32][33];
    int tx = threadIdx.x, ty = threadIdx.y;
    int x = blockIdx.x * 32 + tx;
    int y0 = blockIdx.y * 32;
#pragma unroll
    for (int i = 0; i < 32; i += 8)
        tile[ty + i][tx] = f2bf(in[(size_t)(y0 + ty + i) * C + x]);
    __syncthreads();
    int x2 = y0 + tx;
    int y2 = blockIdx.x * 32;
#pragma unroll
    for (int i = 0; i < 32; i += 8)
        out[(size_t)(y2 + ty + i) * R + x2] = tile[tx][ty + i];
}

// bf16 full transpose: out[c][r] = in[r][c]
__global__ void transpose_bf_k(const ushort_t* __restrict__ in, ushort_t* __restrict__ out,
                               int R, int C) {
    __shared__ ushort_t tile[32][33];
    int tx = threadIdx.x, ty = threadIdx.y;
    int x = blockIdx.x * 32 + tx;
    int y0 = blockIdx.y * 32;
#pragma unroll
    for (int i = 0; i < 32; i += 8)
        tile[ty + i][tx] = in[(size_t)(y0 + ty + i) * C + x];
    __syncthreads();
    int x2 = y0 + tx;
    int y2 = blockIdx.x * 32;
#pragma unroll
    for (int i = 0; i < 32; i += 8)
        out[(size_t)(y2 + ty + i) * R + x2] = tile[tx][ty + i];
}

// ---------------------------------------------------------------------------
// LayerNorm: fp32 input row of 1024, fp32 scale/shift, bf16 output.
// ---------------------------------------------------------------------------
__global__ __launch_bounds__(256) void ln_kernel(const float* __restrict__ xin,
                                                 const float* __restrict__ scale_p,
                                                 const float* __restrict__ shift_p,
                                                 ushort_t* __restrict__ out) {
    int row = blockIdx.x, t = threadIdx.x;
    int wv = t >> 6, lane = t & 63;
    const float* xr = xin + (size_t)row * 1024 + t * 4;
    float4 v = *(const float4*)xr;
    float f[4] = {v.x, v.y, v.z, v.w};
    float s = f[0] + f[1] + f[2] + f[3];
    float q = f[0]*f[0] + f[1]*f[1] + f[2]*f[2] + f[3]*f[3];
#pragma unroll
    for (int off = 1; off < 64; off <<= 1) {
        s += __shfl_xor(s, off, 64);
        q += __shfl_xor(q, off, 64);
    }
    __shared__ float sh_s[4], sh_q[4];
    if (lane == 0) { sh_s[wv] = s; sh_q[wv] = q; }
    __syncthreads();
    float S = sh_s[0] + sh_s[1] + sh_s[2] + sh_s[3];
    float Q = sh_q[0] + sh_q[1] + sh_q[2] + sh_q[3];
    float mean = S * (1.0f / 1024.0f);
    float var = Q * (1.0f / 1024.0f) - mean * mean;
    float rstd = rsqrtf(var + 1e-5f);
    float4 scv = *(const float4*)(scale_p + t * 4);
    float4 shv = *(const float4*)(shift_p + t * 4);
    ushort4 o;
    o.x = f2bf((f[0] - mean) * rstd * scv.x + shv.x);
    o.y = f2bf((f[1] - mean) * rstd * scv.y + shv.y);
    o.z = f2bf((f[2] - mean) * rstd * scv.z + shv.z);
    o.w = f2bf((f[3] - mean) * rstd * scv.w + shv.w);
    *(ushort4*)(out + (size_t)row * 1024 + t * 4) = o;
}

// ---------------------------------------------------------------------------
// GEMM (m97 structure, async global->LDS staging):
// C[M,N] = A[M,K](bf16) @ Bt[N,K](bf16)^T + bias(f32)
// Tile (32*MT) x 128, BK=32, 4 waves 2x2.
// EPI: 1 = +f32 residual, f32 out; 2 = gelu, bf16 out; 3 = QKV split
// ---------------------------------------------------------------------------
template <int MT, int EPI>
__global__ __launch_bounds__(256) void gemm_bt(const ushort_t* __restrict__ A,
                                               const ushort_t* __restrict__ Bt,
                                               const float* __restrict__ b0,
                                               const float* __restrict__ b1,
                                               const float* __restrict__ b2,
                                               const float* __restrict__ res,
                                               void* __restrict__ out0,
                                               void* __restrict__ out1,
                                               void* __restrict__ out2,
                                               int M, int N, int K) {
    __shared__ ushort_t As[32 * MT * 32];
    __shared__ ushort_t Bs[128 * 32];
    const int t = threadIdx.x;
    const int wv = t >> 6, lane = t & 63, lo = lane & 15, hi = lane >> 4;
    const int wr = wv >> 1, wc = wv & 1;
    const int mb = blockIdx.y, nb = blockIdx.x;

    f32x4 acc[MT][4];
#pragma unroll
    for (int i = 0; i < MT; ++i)
#pragma unroll
        for (int j = 0; j < 4; ++j) acc[i][j] = (f32x4){0.f, 0.f, 0.f, 0.f};

    for (int k0 = 0; k0 < K; k0 += 32) {
#pragma unroll
        for (int i = 0; i < MT / 2; ++i) {
            int c = i * 256 + t;
            int row = c >> 2, kc = c & 3;
            async16((char*)As + (size_t)(i * 256 + wv * 64) * 16,
                    A + (size_t)(mb * 32 * MT + row) * K + k0 + kc * 8);
        }
#pragma unroll
        for (int i = 0; i < 2; ++i) {
            int c = i * 256 + t;
            int row = c >> 2, kc = c & 3;
            async16((char*)Bs + (size_t)(i * 256 + wv * 64) * 16,
                    Bt + (size_t)(nb * 128 + row) * K + k0 + kc * 8);
        }
        __syncthreads();

        short8 af[MT], bfr[4];
#pragma unroll
        for (int mi = 0; mi < MT; ++mi)
            af[mi] = *(const short8*)(As + (wr * 16 * MT + mi * 16 + lo) * 32 + hi * 8);
#pragma unroll
        for (int ni = 0; ni < 4; ++ni)
            bfr[ni] = *(const short8*)(Bs + (wc * 64 + ni * 16 + lo) * 32 + hi * 8);
#pragma unroll
        for (int mi = 0; mi < MT; ++mi)
#pragma unroll
            for (int ni = 0; ni < 4; ++ni)
                acc[mi][ni] = __builtin_amdgcn_mfma_f32_16x16x32_bf16(
                    af[mi], bfr[ni], acc[mi][ni], 0, 0, 0);
        __syncthreads();
    }

#pragma unroll
    for (int ni = 0; ni < 4; ++ni) {
        int n = nb * 128 + wc * 64 + ni * 16 + lo;
        float bn;
        ushort_t* obf = nullptr;
        int coln = n;
        if (EPI == 3) {
            int seg = n >> 10; coln = n & 1023;
            bn = (seg == 0 ? b0 : seg == 1 ? b1 : b2)[coln];
            obf = (ushort_t*)(seg == 0 ? out0 : seg == 1 ? out1 : out2);
        } else {
            bn = b0[n];
        }
#pragma unroll
        for (int mi = 0; mi < MT; ++mi) {
#pragma unroll
            for (int r = 0; r < 4; ++r) {
                int m = mb * 32 * MT + wr * 16 * MT + mi * 16 + 4 * hi + r;
                float v = acc[mi][ni][r] + bn;
                if (EPI == 1) {
                    size_t idx = (size_t)m * N + n;
                    ((float*)out0)[idx] = v + res[idx];
                } else if (EPI == 2) {
                    v = 0.5f * v * (1.0f + erff(v * 0.70710678118654752f));
                    ((ushort_t*)out0)[(size_t)m * N + n] = f2bf(v);
                } else {
                    obf[(size_t)m * 1024 + coln] = f2bf(v);
                }
            }
        }
    }
}

// ---------------------------------------------------------------------------
// Causal flash attention v3. One block per (128 q-rows, b*h), 4 waves; wave
// owns 2 groups of 16 q-rows. Double-buffered K/V^T staging (async16), one
// barrier per k-tile. QK computed operand-swapped (S^T = K x Q^T) so softmax
// stats are in-lane (+2 shuffles). P -> per-wave LDS -> A-operand for PV.
// Softmax in exp2 domain (0.125*log2e folded).
// ---------------------------------------------------------------------------
__global__ __launch_bounds__(256) void attn_kernel(const ushort_t* __restrict__ q,
                                                   const ushort_t* __restrict__ k,
                                                   const ushort_t* __restrict__ vt,
                                                   ushort_t* __restrict__ ctx) {
    __shared__ ushort_t Ks[2][64 * 64];   // [buf][key][d], col-chunk swizzled
    __shared__ ushort_t VTs[2][64 * 64];  // [buf][d][key], col-chunk swizzled
    __shared__ ushort_t Ps[8][16 * 72];   // [wave*2+g][qrow][key], stride 72

    const int t = threadIdx.x;
    const int wv = t >> 6, lane = t & 63, lo = lane & 15, hi = lane >> 4;
    const int qb = (int)gridDim.x - 1 - (int)blockIdx.x;   // heavy blocks first
    const int bh = blockIdx.y, b = bh >> 4, h = bh & 15;
    const int q0 = qb * 128;
    const size_t headoff = (size_t)h * 64;
    const size_t rowbase = (size_t)b * T_ * 1024;
    const ushort_t* vbase = vt + headoff * (size_t)M_ + (size_t)b * T_;

    // Q fragments (B-operand pattern == A pattern: row qg0+lo, k-contig)
    short8 qf[2][2];
#pragma unroll
    for (int g = 0; g < 2; ++g) {
        const ushort_t* qp = q + rowbase + (size_t)(q0 + g * 64 + wv * 16 + lo) * 1024 + headoff;
        qf[g][0] = *(const short8*)(qp + hi * 8);
        qf[g][1] = *(const short8*)(qp + 32 + hi * 8);
    }

    float m_g[2], l_g[2];
    f32x4 o_acc[2][4];
#pragma unroll
    for (int g = 0; g < 2; ++g) {
        m_g[g] = -1e30f; l_g[g] = 0.f;
#pragma unroll
        for (int dt = 0; dt < 4; ++dt) o_acc[g][dt] = (f32x4){0.f, 0.f, 0.f, 0.f};
    }

    const int ktmax = 2 * qb + 1;
    const float SC = 0.18033688011112042f;  // 0.125 * log2(e)

    // stage tile kt into buffer bb: 512 x 16B chunks each for K and VT
    auto stage = [&](int bb, int kt) {
        const int k0 = kt * 64;
#pragma unroll
        for (int i = 0; i < 2; ++i) {
            int c = i * 256 + t;
            int row = c >> 3, c8 = c & 7;
            int gsw = c8 ^ (row & 7);
            async16((char*)&Ks[bb][0] + (size_t)(i * 256 + wv * 64) * 16,
                    k + rowbase + (size_t)(k0 + row) * 1024 + headoff + gsw * 8);
            async16((char*)&VTs[bb][0] + (size_t)(i * 256 + wv * 64) * 16,
                    vbase + (size_t)row * M_ + k0 + gsw * 8);
        }
    };

    stage(0, 0);
    for (int kt = 0; kt <= ktmax; ++kt) {
        const int bb = kt & 1;
        const int k0 = kt * 64;
        __syncthreads();                    // staged tile bb ready; prev reads done
        if (kt < ktmax) stage(bb ^ 1, kt + 1);

        short8 pf[2][2];
        int any_g[2];
#pragma unroll
        for (int g = 0; g < 2; ++g) {
            const int qg0 = q0 + g * 64 + wv * 16;
            const int diff = qg0 - k0;
            any_g[g] = (diff >= 0);
            if (!any_g[g]) continue;
            const int cmax = diff >= 48 ? 3 : (diff >> 4);

            // S^T = K x Q^T  (A=K frag, B=Q frag) -> lane holds qrow=qg0+lo,
            // 16 keys {16*kt16 + 4*hi + r}
            f32x4 sacc[4];
#pragma unroll
            for (int kt16 = 0; kt16 < 4; ++kt16) {
                if (kt16 <= cmax) {
                    int row = kt16 * 16 + lo, sw = row & 7;
                    short8 kf0 = *(const short8*)(&Ks[bb][0] + row * 64 + (hi ^ sw) * 8);
                    short8 kf1 = *(const short8*)(&Ks[bb][0] + row * 64 + ((4 + hi) ^ sw) * 8);
                    f32x4 z = (f32x4){0.f, 0.f, 0.f, 0.f};
                    z = __builtin_amdgcn_mfma_f32_16x16x32_bf16(kf0, qf[g][0], z, 0, 0, 0);
                    z = __builtin_amdgcn_mfma_f32_16x16x32_bf16(kf1, qf[g][1], z, 0, 0, 0);
#pragma unroll
                    for (int r = 0; r < 4; ++r) sacc[kt16][r] = z[r] * SC;
                } else {
                    sacc[kt16] = (f32x4){-1e30f, -1e30f, -1e30f, -1e30f};
                }
            }
            if (diff < 64) {  // diagonal subtile: element mask key > qrow
                const int qrow = qg0 + lo;
#pragma unroll
                for (int r = 0; r < 4; ++r) {
                    int key = k0 + cmax * 16 + 4 * hi + r;
                    if (key > qrow) sacc[cmax][r] = -1e30f;
                }
            }

            // in-lane row max + 2-shuffle reduce (replicated across hi groups)
            float mx = -1e30f;
#pragma unroll
            for (int kt16 = 0; kt16 < 4; ++kt16)
#pragma unroll
                for (int r = 0; r < 4; ++r) mx = fmaxf(mx, sacc[kt16][r]);
            mx = fmaxf(mx, __shfl_xor(mx, 16, 64));
            mx = fmaxf(mx, __shfl_xor(mx, 32, 64));
            float mnew = fmaxf(m_g[g], mx);
            float alpha = fexp2(m_g[g] - mnew);
            m_g[g] = mnew;

            ushort_t* Pw = Ps[wv * 2 + g];
            float rs = 0.f;
#pragma unroll
            for (int kt16 = 0; kt16 < 4; ++kt16)
#pragma unroll
                for (int r = 0; r < 4; ++r) {
                    float p = fexp2(sacc[kt16][r] - mnew);
                    rs += p;
                    Pw[lo * 72 + kt16 * 16 + 4 * hi + r] = f2bf(p);
                }
            rs += __shfl_xor(rs, 16, 64);
            rs += __shfl_xor(rs, 32, 64);
            l_g[g] = l_g[g] * alpha + rs;

            // broadcast alpha to o_acc's row owners (row = 4*hi + r)
#pragma unroll
            for (int r = 0; r < 4; ++r) {
                float ab = __shfl(alpha, 4 * hi + r, 64);
#pragma unroll
                for (int dt = 0; dt < 4; ++dt) o_acc[g][dt][r] *= ab;
            }

            pf[g][0] = *(const short8*)(Pw + lo * 72 + hi * 8);
            pf[g][1] = *(const short8*)(Pw + lo * 72 + 32 + hi * 8);
        }

        // PV: V^T fragments shared across both groups
#pragma unroll
        for (int dt = 0; dt < 4; ++dt) {
            int row = dt * 16 + lo, sw = row & 7;
            short8 vf0 = *(const short8*)(&VTs[bb][0] + row * 64 + (hi ^ sw) * 8);
            short8 vf1 = *(const short8*)(&VTs[bb][0] + row * 64 + ((4 + hi) ^ sw) * 8);
#pragma unroll
            for (int g = 0; g < 2; ++g) {
                if (!any_g[g]) continue;
                o_acc[g][dt] = __builtin_amdgcn_mfma_f32_16x16x32_bf16(pf[g][0], vf0, o_acc[g][dt], 0, 0, 0);
                o_acc[g][dt] = __builtin_amdgcn_mfma_f32_16x16x32_bf16(pf[g][1], vf1, o_acc[g][dt], 0, 0, 0);
            }
        }
    }

#pragma unroll
    for (int g = 0; g < 2; ++g) {
#pragma unroll
        for (int r = 0; r < 4; ++r) {
            float lb = __shfl(l_g[g], 4 * hi + r, 64);
            float inv = 1.0f / lb;
            size_t row = rowbase + (size_t)(q0 + g * 64 + wv * 16 + 4 * hi + r) * 1024 + headoff;
#pragma unroll
            for (int dt = 0; dt < 4; ++dt)
                ctx[row + dt * 16 + lo] = f2bf(o_acc[g][dt][r] * inv);
        }
    }
}

// ---------------------------------------------------------------------------
extern "C" void kernel_launch(void* const* d_in, const int* in_sizes, int n_in,
                              void* d_out, int out_size, void* d_ws, size_t ws_size,
                              hipStream_t stream) {
    (void)in_sizes; (void)n_in; (void)out_size; (void)ws_size;
    const float* x    = (const float*)d_in[0];
    const float* Wq   = (const float*)d_in[1];
    const float* bq   = (const float*)d_in[2];
    const float* Wk   = (const float*)d_in[3];
    const float* bk   = (const float*)d_in[4];
    const float* Wv   = (const float*)d_in[5];
    const float* bv   = (const float*)d_in[6];
    const float* Wo   = (const float*)d_in[7];
    const float* bo   = (const float*)d_in[8];
    const float* W1   = (const float*)d_in[9];
    const float* b1   = (const float*)d_in[10];
    const float* W2   = (const float*)d_in[11];
    const float* b2   = (const float*)d_in[12];
    const float* ln1s = (const float*)d_in[13];
    const float* ln1b = (const float*)d_in[14];
    const float* ln2s = (const float*)d_in[15];
    const float* ln2b = (const float*)d_in[16];

    char* ws = (char*)d_ws;
    const size_t MB = 1024 * 1024;
    ushort_t* wqkv = (ushort_t*)(ws + 0 * MB);   // wtq|wtk|wtv contiguous [3072][1024]
    ushort_t* wtq  = (ushort_t*)(ws + 0 * MB);
    ushort_t* wtk  = (ushort_t*)(ws + 2 * MB);
    ushort_t* wtv  = (ushort_t*)(ws + 4 * MB);
    ushort_t* wto  = (ushort_t*)(ws + 6 * MB);
    ushort_t* wt1  = (ushort_t*)(ws + 8 * MB);   // 8MB (4096x1024)
    ushort_t* wt2  = (ushort_t*)(ws + 16 * MB);  // 8MB (1024x4096)
    ushort_t* hbuf = (ushort_t*)(ws + 24 * MB);  // 8MB
    ushort_t* qb_  = (ushort_t*)(ws + 32 * MB);  // 8MB
    ushort_t* kb_  = (ushort_t*)(ws + 40 * MB);  // 8MB
    ushort_t* vb_  = (ushort_t*)(ws + 48 * MB);  // 8MB
    ushort_t* ctx  = (ushort_t*)(ws + 56 * MB);  // 8MB
    ushort_t* hid  = (ushort_t*)(ws + 32 * MB);  // 32MB, reuses qkv/ctx post-attn
    float*    x1   = (float*)(ws + 64 * MB);     // 16MB fp32 (written after attn)
    ushort_t* vtb  = (ushort_t*)(ws + 64 * MB);  // 8MB [1024][4096], dead after Wo

    dim3 tb(32, 8);
    transpose_cast_k<<<dim3(32, 32), tb, 0, stream>>>(Wq, wtq, 1024, 1024);
    transpose_cast_k<<<dim3(32, 32), tb, 0, stream>>>(Wk, wtk, 1024, 1024);
    transpose_cast_k<<<dim3(32, 32), tb, 0, stream>>>(Wv, wtv, 1024, 1024);
    transpose_cast_k<<<dim3(32, 32), tb, 0, stream>>>(Wo, wto, 1024, 1024);
    transpose_cast_k<<<dim3(128, 32), tb, 0, stream>>>(W1, wt1, 1024, 4096);
    transpose_cast_k<<<dim3(32, 128), tb, 0, stream>>>(W2, wt2, 4096, 1024);

    ln_kernel<<<4096, 256, 0, stream>>>(x, ln1s, ln1b, hbuf);

    gemm_bt<4, 3><<<dim3(24, 32), 256, 0, stream>>>(hbuf, wqkv, bq, bk, bv, nullptr,
                                                    qb_, kb_, vb_, 4096, 3072, 1024);

    transpose_bf_k<<<dim3(32, 128), tb, 0, stream>>>(vb_, vtb, 4096, 1024);

    attn_kernel<<<dim3(16, 32), 256, 0, stream>>>(qb_, kb_, vtb, ctx);

    gemm_bt<2, 1><<<dim3(8, 64), 256, 0, stream>>>(ctx, wto, bo, nullptr, nullptr, x,
                                                   x1, nullptr, nullptr, 4096, 1024, 1024);

    ln_kernel<<<4096, 256, 0, stream>>>(x1, ln2s, ln2b, hbuf);

    gemm_bt<4, 2><<<dim3(32, 32), 256, 0, stream>>>(hbuf, wt1, b1, nullptr, nullptr, nullptr,
                                                    hid, nullptr, nullptr, 4096, 4096, 1024);

    gemm_bt<2, 1><<<dim3(8, 64), 256, 0, stream>>>(hid, wt2, b2, nullptr, nullptr, x1,
                                                   (float*)d_out, nullptr, nullptr, 4096, 1024, 4096);
}

// Round 9
// 439.852 us; speedup vs baseline: 1.3378x; 1.0387x over previous
//
#include <hip/hip_runtime.h>
#include <hip/hip_bf16.h>
#include <stdint.h>

#define B_ 2
#define T_ 2048
#define C_ 1024
#define H_ 16
#define D_ 64
#define F_ 4096
#define M_ (B_*T_)

typedef unsigned short ushort_t;
typedef __attribute__((ext_vector_type(8))) short short8;
typedef __attribute__((ext_vector_type(4))) float f32x4;

__device__ __forceinline__ float bf2f(ushort_t u) {
    union { unsigned u; float f; } c; c.u = ((unsigned)u) << 16; return c.f;
}
__device__ __forceinline__ ushort_t f2bf(float f) {
    union { float f; unsigned u; } c; c.f = f;
    unsigned u = c.u;
    unsigned r = (u + 0x7FFFu + ((u >> 16) & 1u)) >> 16;
    return (ushort_t)r;
}

__device__ __forceinline__ float fexp2(float x) { return __builtin_amdgcn_exp2f(x); }

// async global->LDS, 16B per lane. LDS dest = wave-uniform base + lane*16.
__device__ __forceinline__ void async16(void* lds, const void* g) {
    __builtin_amdgcn_global_load_lds(
        (const __attribute__((address_space(1))) unsigned int*)(uintptr_t)g,
        (__attribute__((address_space(3))) unsigned int*)(uintptr_t)lds,
        16, 0, 0);
}

// ---------------------------------------------------------------------------
// Batched transpose+cast of all 6 weights: out_bf16[c][r] = in_f32[r][c]
// ---------------------------------------------------------------------------
__global__ __launch_bounds__(256) void transpose_all_k(
    const float* __restrict__ Wq, const float* __restrict__ Wk,
    const float* __restrict__ Wv, const float* __restrict__ Wo,
    const float* __restrict__ W1, const float* __restrict__ W2,
    ushort_t* __restrict__ oq, ushort_t* __restrict__ ok,
    ushort_t* __restrict__ ov, ushort_t* __restrict__ oo,
    ushort_t* __restrict__ o1, ushort_t* __restrict__ o2) {
    __shared__ ushort_t tile[32][33];
    int id = blockIdx.x;
    const float* in; ushort_t* out; int R, Cc, bx, by;
    if (id < 4096) {
        int w = id >> 10, loc = id & 1023;
        in  = w == 0 ? Wq : w == 1 ? Wk : w == 2 ? Wv : Wo;
        out = w == 0 ? oq : w == 1 ? ok : w == 2 ? ov : oo;
        R = 1024; Cc = 1024; bx = loc & 31; by = loc >> 5;
    } else if (id < 8192) {
        int loc = id - 4096; in = W1; out = o1; R = 1024; Cc = 4096;
        bx = loc & 127; by = loc >> 7;
    } else {
        int loc = id - 8192; in = W2; out = o2; R = 4096; Cc = 1024;
        bx = loc & 31; by = loc >> 5;
    }
    int tx = threadIdx.x, ty = threadIdx.y;
    int x = bx * 32 + tx;
    int y0 = by * 32;
#pragma unroll
    for (int i = 0; i < 32; i += 8)
        tile[ty + i][tx] = f2bf(in[(size_t)(y0 + ty + i) * Cc + x]);
    __syncthreads();
    int x2 = y0 + tx;
    int y2 = bx * 32;
#pragma unroll
    for (int i = 0; i < 32; i += 8)
        out[(size_t)(y2 + ty + i) * R + x2] = tile[tx][ty + i];
}

// ---------------------------------------------------------------------------
// LayerNorm: fp32 input row of 1024, fp32 scale/shift, bf16 output.
// ---------------------------------------------------------------------------
__global__ __launch_bounds__(256) void ln_kernel(const float* __restrict__ xin,
                                                 const float* __restrict__ scale_p,
                                                 const float* __restrict__ shift_p,
                                                 ushort_t* __restrict__ out) {
    int row = blockIdx.x, t = threadIdx.x;
    int wv = t >> 6, lane = t & 63;
    const float* xr = xin + (size_t)row * 1024 + t * 4;
    float4 v = *(const float4*)xr;
    float f[4] = {v.x, v.y, v.z, v.w};
    float s = f[0] + f[1] + f[2] + f[3];
    float q = f[0]*f[0] + f[1]*f[1] + f[2]*f[2] + f[3]*f[3];
#pragma unroll
    for (int off = 1; off < 64; off <<= 1) {
        s += __shfl_xor(s, off, 64);
        q += __shfl_xor(q, off, 64);
    }
    __shared__ float sh_s[4], sh_q[4];
    if (lane == 0) { sh_s[wv] = s; sh_q[wv] = q; }
    __syncthreads();
    float S = sh_s[0] + sh_s[1] + sh_s[2] + sh_s[3];
    float Q = sh_q[0] + sh_q[1] + sh_q[2] + sh_q[3];
    float mean = S * (1.0f / 1024.0f);
    float var = Q * (1.0f / 1024.0f) - mean * mean;
    float rstd = rsqrtf(var + 1e-5f);
    float4 scv = *(const float4*)(scale_p + t * 4);
    float4 shv = *(const float4*)(shift_p + t * 4);
    ushort4 o;
    o.x = f2bf((f[0] - mean) * rstd * scv.x + shv.x);
    o.y = f2bf((f[1] - mean) * rstd * scv.y + shv.y);
    o.z = f2bf((f[2] - mean) * rstd * scv.z + shv.z);
    o.w = f2bf((f[3] - mean) * rstd * scv.w + shv.w);
    *(ushort4*)(out + (size_t)row * 1024 + t * 4) = o;
}

// ---------------------------------------------------------------------------
// GEMM (m97 structure, async global->LDS staging):
// C[M,N] = A[M,K](bf16) @ Bt[N,K](bf16)^T + bias(f32)
// Tile (32*MT) x 128, BK=32, 4 waves 2x2.
// EPI: 1 = +f32 residual, f32 out; 2 = gelu, bf16 out
//      3 = QKV split: seg0/1 -> q,k row-major bf16; seg2 -> v transposed
// ---------------------------------------------------------------------------
template <int MT, int EPI>
__global__ __launch_bounds__(256) void gemm_bt(const ushort_t* __restrict__ A,
                                               const ushort_t* __restrict__ Bt,
                                               const float* __restrict__ b0,
                                               const float* __restrict__ b1,
                                               const float* __restrict__ b2,
                                               const float* __restrict__ res,
                                               void* __restrict__ out0,
                                               void* __restrict__ out1,
                                               void* __restrict__ out2,
                                               int M, int N, int K) {
    __shared__ ushort_t As[32 * MT * 32];
    __shared__ ushort_t Bs[128 * 32];
    const int t = threadIdx.x;
    const int wv = t >> 6, lane = t & 63, lo = lane & 15, hi = lane >> 4;
    const int wr = wv >> 1, wc = wv & 1;
    const int mb = blockIdx.y, nb = blockIdx.x;

    f32x4 acc[MT][4];
#pragma unroll
    for (int i = 0; i < MT; ++i)
#pragma unroll
        for (int j = 0; j < 4; ++j) acc[i][j] = (f32x4){0.f, 0.f, 0.f, 0.f};

    for (int k0 = 0; k0 < K; k0 += 32) {
#pragma unroll
        for (int i = 0; i < MT / 2; ++i) {
            int c = i * 256 + t;
            int row = c >> 2, kc = c & 3;
            async16((char*)As + (size_t)(i * 256 + wv * 64) * 16,
                    A + (size_t)(mb * 32 * MT + row) * K + k0 + kc * 8);
        }
#pragma unroll
        for (int i = 0; i < 2; ++i) {
            int c = i * 256 + t;
            int row = c >> 2, kc = c & 3;
            async16((char*)Bs + (size_t)(i * 256 + wv * 64) * 16,
                    Bt + (size_t)(nb * 128 + row) * K + k0 + kc * 8);
        }
        __syncthreads();

        short8 af[MT], bfr[4];
#pragma unroll
        for (int mi = 0; mi < MT; ++mi)
            af[mi] = *(const short8*)(As + (wr * 16 * MT + mi * 16 + lo) * 32 + hi * 8);
#pragma unroll
        for (int ni = 0; ni < 4; ++ni)
            bfr[ni] = *(const short8*)(Bs + (wc * 64 + ni * 16 + lo) * 32 + hi * 8);
#pragma unroll
        for (int mi = 0; mi < MT; ++mi)
#pragma unroll
            for (int ni = 0; ni < 4; ++ni)
                acc[mi][ni] = __builtin_amdgcn_mfma_f32_16x16x32_bf16(
                    af[mi], bfr[ni], acc[mi][ni], 0, 0, 0);
        __syncthreads();
    }

#pragma unroll
    for (int ni = 0; ni < 4; ++ni) {
        int n = nb * 128 + wc * 64 + ni * 16 + lo;
        float bn;
        ushort_t* obf = nullptr;
        int coln = n, seg = 0;
        if (EPI == 3) {
            seg = n >> 10; coln = n & 1023;
            bn = (seg == 0 ? b0 : seg == 1 ? b1 : b2)[coln];
            obf = (ushort_t*)(seg == 0 ? out0 : out1);
        } else {
            bn = b0[n];
        }
#pragma unroll
        for (int mi = 0; mi < MT; ++mi) {
            if (EPI == 3 && seg == 2) {
                int m0 = mb * 32 * MT + wr * 16 * MT + mi * 16 + 4 * hi;
                ushort4 pk;
                pk.x = f2bf(acc[mi][ni][0] + bn);
                pk.y = f2bf(acc[mi][ni][1] + bn);
                pk.z = f2bf(acc[mi][ni][2] + bn);
                pk.w = f2bf(acc[mi][ni][3] + bn);
                *(ushort4*)((ushort_t*)out2 + (size_t)coln * M + m0) = pk;
            } else {
#pragma unroll
                for (int r = 0; r < 4; ++r) {
                    int m = mb * 32 * MT + wr * 16 * MT + mi * 16 + 4 * hi + r;
                    float v = acc[mi][ni][r] + bn;
                    if (EPI == 1) {
                        size_t idx = (size_t)m * N + n;
                        ((float*)out0)[idx] = v + res[idx];
                    } else if (EPI == 2) {
                        v = 0.5f * v * (1.0f + erff(v * 0.70710678118654752f));
                        ((ushort_t*)out0)[(size_t)m * N + n] = f2bf(v);
                    } else {
                        obf[(size_t)m * 1024 + coln] = f2bf(v);
                    }
                }
            }
        }
    }
}

// ---------------------------------------------------------------------------
// Causal flash attention v3 (VERBATIM from R6 green run @99us).
// One block per (128 q-rows, b*h), 4 waves; wave owns 2 groups of 16 q-rows.
// Double-buffered K/V^T staging, 1 barrier/tile. S^T = K x Q^T operand swap.
// ---------------------------------------------------------------------------
__global__ __launch_bounds__(256) void attn_kernel(const ushort_t* __restrict__ q,
                                                   const ushort_t* __restrict__ k,
                                                   const ushort_t* __restrict__ vt,
                                                   ushort_t* __restrict__ ctx) {
    __shared__ ushort_t Ks[2][64 * 64];   // [buf][key][d], col-chunk swizzled
    __shared__ ushort_t VTs[2][64 * 64];  // [buf][d][key], col-chunk swizzled
    __shared__ ushort_t Ps[8][16 * 72];   // [wave*2+g][qrow][key], stride 72

    const int t = threadIdx.x;
    const int wv = t >> 6, lane = t & 63, lo = lane & 15, hi = lane >> 4;
    const int qb = (int)gridDim.x - 1 - (int)blockIdx.x;   // heavy blocks first
    const int bh = blockIdx.y, b = bh >> 4, h = bh & 15;
    const int q0 = qb * 128;
    const size_t headoff = (size_t)h * 64;
    const size_t rowbase = (size_t)b * T_ * 1024;
    const ushort_t* vbase = vt + headoff * (size_t)M_ + (size_t)b * T_;

    short8 qf[2][2];
#pragma unroll
    for (int g = 0; g < 2; ++g) {
        const ushort_t* qp = q + rowbase + (size_t)(q0 + g * 64 + wv * 16 + lo) * 1024 + headoff;
        qf[g][0] = *(const short8*)(qp + hi * 8);
        qf[g][1] = *(const short8*)(qp + 32 + hi * 8);
    }

    float m_g[2], l_g[2];
    f32x4 o_acc[2][4];
#pragma unroll
    for (int g = 0; g < 2; ++g) {
        m_g[g] = -1e30f; l_g[g] = 0.f;
#pragma unroll
        for (int dt = 0; dt < 4; ++dt) o_acc[g][dt] = (f32x4){0.f, 0.f, 0.f, 0.f};
    }

    const int ktmax = 2 * qb + 1;
    const float SC = 0.18033688011112042f;  // 0.125 * log2(e)
    const f32x4 NEG4 = (f32x4){-1e30f, -1e30f, -1e30f, -1e30f};

    auto stage = [&](int bb, int kt) {
        const int k0s = kt * 64;
#pragma unroll
        for (int i = 0; i < 2; ++i) {
            int c = i * 256 + t;
            int row = c >> 3, c8 = c & 7;
            int gsw = c8 ^ (row & 7);
            async16((char*)&Ks[bb][0] + (size_t)(i * 256 + wv * 64) * 16,
                    k + rowbase + (size_t)(k0s + row) * 1024 + headoff + gsw * 8);
            async16((char*)&VTs[bb][0] + (size_t)(i * 256 + wv * 64) * 16,
                    vbase + (size_t)row * M_ + k0s + gsw * 8);
        }
    };

    // online softmax update for one group: consumes sacc, writes P,
    // rescales o_acc, updates m/l.
    auto softmax_g = [&](f32x4* sacc, int gi) {
        float mx = -1e30f;
#pragma unroll
        for (int kt16 = 0; kt16 < 4; ++kt16)
#pragma unroll
            for (int r = 0; r < 4; ++r) mx = fmaxf(mx, sacc[kt16][r]);
        mx = fmaxf(mx, __shfl_xor(mx, 16, 64));
        mx = fmaxf(mx, __shfl_xor(mx, 32, 64));
        float mnew = fmaxf(m_g[gi], mx);
        float alpha = fexp2(m_g[gi] - mnew);
        m_g[gi] = mnew;
        ushort_t* Pw = Ps[wv * 2 + gi];
        float rs = 0.f;
#pragma unroll
        for (int kt16 = 0; kt16 < 4; ++kt16) {
#pragma unroll
            for (int r = 0; r < 4; ++r) {
                float p = fexp2(sacc[kt16][r] - mnew);
                rs += p;
                Pw[lo * 72 + kt16 * 16 + 4 * hi + r] = f2bf(p);
            }
        }
        rs += __shfl_xor(rs, 16, 64);
        rs += __shfl_xor(rs, 32, 64);
        l_g[gi] = l_g[gi] * alpha + rs;
#pragma unroll
        for (int r = 0; r < 4; ++r) {
            float ab = __shfl(alpha, 4 * hi + r, 64);
#pragma unroll
            for (int dt = 0; dt < 4; ++dt) o_acc[gi][dt][r] *= ab;
        }
    };

    stage(0, 0);
    for (int kt = 0; kt <= ktmax; ++kt) {
        const int bb = kt & 1;
        const int k0 = kt * 64;
        __syncthreads();
        if (kt < ktmax) stage(bb ^ 1, kt + 1);

        short8 pf[2][2];
        int any_g[2];
#pragma unroll
        for (int g = 0; g < 2; ++g) {
            const int qg0 = q0 + g * 64 + wv * 16;
            const int diff = qg0 - k0;
            any_g[g] = (diff >= 0);
            if (!any_g[g]) continue;
            const int cmax = diff >= 48 ? 3 : (diff >> 4);

            f32x4 sacc[4];
#pragma unroll
            for (int kt16 = 0; kt16 < 4; ++kt16) {
                if (kt16 <= cmax) {
                    int row = kt16 * 16 + lo, sw = row & 7;
                    short8 kf0 = *(const short8*)(&Ks[bb][0] + row * 64 + (hi ^ sw) * 8);
                    short8 kf1 = *(const short8*)(&Ks[bb][0] + row * 64 + ((4 + hi) ^ sw) * 8);
                    f32x4 z = (f32x4){0.f, 0.f, 0.f, 0.f};
                    z = __builtin_amdgcn_mfma_f32_16x16x32_bf16(kf0, qf[g][0], z, 0, 0, 0);
                    z = __builtin_amdgcn_mfma_f32_16x16x32_bf16(kf1, qf[g][1], z, 0, 0, 0);
#pragma unroll
                    for (int r = 0; r < 4; ++r) sacc[kt16][r] = z[r] * SC;
                } else {
                    sacc[kt16] = NEG4;
                }
            }
            if (diff < 64) {  // diagonal subtile: element mask key > qrow
                const int qrow = diff + lo;
#pragma unroll
                for (int r = 0; r < 4; ++r) {
                    int key = cmax * 16 + 4 * hi + r;
                    if (key > qrow) sacc[cmax][r] = -1e30f;
                }
            }

            softmax_g(sacc, g);

            pf[g][0] = *(const short8*)(Ps[wv * 2 + g] + lo * 72 + hi * 8);
            pf[g][1] = *(const short8*)(Ps[wv * 2 + g] + lo * 72 + 32 + hi * 8);
        }

        // PV: V^T fragments shared across both groups
#pragma unroll
        for (int dt = 0; dt < 4; ++dt) {
            int row = dt * 16 + lo, sw = row & 7;
            short8 vf0 = *(const short8*)(&VTs[bb][0] + row * 64 + (hi ^ sw) * 8);
            short8 vf1 = *(const short8*)(&VTs[bb][0] + row * 64 + ((4 + hi) ^ sw) * 8);
#pragma unroll
            for (int g = 0; g < 2; ++g) {
                if (!any_g[g]) continue;
                o_acc[g][dt] = __builtin_amdgcn_mfma_f32_16x16x32_bf16(pf[g][0], vf0, o_acc[g][dt], 0, 0, 0);
                o_acc[g][dt] = __builtin_amdgcn_mfma_f32_16x16x32_bf16(pf[g][1], vf1, o_acc[g][dt], 0, 0, 0);
            }
        }
    }

#pragma unroll
    for (int g = 0; g < 2; ++g) {
#pragma unroll
        for (int r = 0; r < 4; ++r) {
            float lb = __shfl(l_g[g], 4 * hi + r, 64);
            float inv = 1.0f / lb;
            size_t row = rowbase + (size_t)(q0 + g * 64 + wv * 16 + 4 * hi + r) * 1024 + headoff;
#pragma unroll
            for (int dt = 0; dt < 4; ++dt)
                ctx[row + dt * 16 + lo] = f2bf(o_acc[g][dt][r] * inv);
        }
    }
}

// ---------------------------------------------------------------------------
extern "C" void kernel_launch(void* const* d_in, const int* in_sizes, int n_in,
                              void* d_out, int out_size, void* d_ws, size_t ws_size,
                              hipStream_t stream) {
    (void)in_sizes; (void)n_in; (void)out_size; (void)ws_size;
    const float* x    = (const float*)d_in[0];
    const float* Wq   = (const float*)d_in[1];
    const float* bq   = (const float*)d_in[2];
    const float* Wk   = (const float*)d_in[3];
    const float* bk   = (const float*)d_in[4];
    const float* Wv   = (const float*)d_in[5];
    const float* bv   = (const float*)d_in[6];
    const float* Wo   = (const float*)d_in[7];
    const float* bo   = (const float*)d_in[8];
    const float* W1   = (const float*)d_in[9];
    const float* b1   = (const float*)d_in[10];
    const float* W2   = (const float*)d_in[11];
    const float* b2   = (const float*)d_in[12];
    const float* ln1s = (const float*)d_in[13];
    const float* ln1b = (const float*)d_in[14];
    const float* ln2s = (const float*)d_in[15];
    const float* ln2b = (const float*)d_in[16];

    char* ws = (char*)d_ws;
    const size_t MB = 1024 * 1024;
    ushort_t* wqkv = (ushort_t*)(ws + 0 * MB);   // wtq|wtk|wtv contiguous [3072][1024]
    ushort_t* wtq  = (ushort_t*)(ws + 0 * MB);
    ushort_t* wtk  = (ushort_t*)(ws + 2 * MB);
    ushort_t* wtv  = (ushort_t*)(ws + 4 * MB);
    ushort_t* wto  = (ushort_t*)(ws + 6 * MB);
    ushort_t* wt1  = (ushort_t*)(ws + 8 * MB);   // 8MB (4096x1024)
    ushort_t* wt2  = (ushort_t*)(ws + 16 * MB);  // 8MB (1024x4096)
    ushort_t* hbuf = (ushort_t*)(ws + 24 * MB);  // 8MB
    ushort_t* qb_  = (ushort_t*)(ws + 32 * MB);  // 8MB
    ushort_t* kb_  = (ushort_t*)(ws + 40 * MB);  // 8MB
    ushort_t* ctx  = (ushort_t*)(ws + 56 * MB);  // 8MB
    ushort_t* hid  = (ushort_t*)(ws + 32 * MB);  // 32MB, reuses q/k/ctx post-attn
    float*    x1   = (float*)(ws + 64 * MB);     // 16MB fp32 (written after attn)
    ushort_t* vtb  = (ushort_t*)(ws + 64 * MB);  // 8MB [1024][4096], dead after attn

    transpose_all_k<<<12288, dim3(32, 8), 0, stream>>>(Wq, Wk, Wv, Wo, W1, W2,
                                                       wtq, wtk, wtv, wto, wt1, wt2);

    ln_kernel<<<4096, 256, 0, stream>>>(x, ln1s, ln1b, hbuf);

    // fused QKV; seg2 writes v^T directly into vtb [1024][4096]
    gemm_bt<4, 3><<<dim3(24, 32), 256, 0, stream>>>(hbuf, wqkv, bq, bk, bv, nullptr,
                                                    qb_, kb_, vtb, 4096, 3072, 1024);

    attn_kernel<<<dim3(16, 32), 256, 0, stream>>>(qb_, kb_, vtb, ctx);

    gemm_bt<2, 1><<<dim3(8, 64), 256, 0, stream>>>(ctx, wto, bo, nullptr, nullptr, x,
                                                   x1, nullptr, nullptr, 4096, 1024, 1024);

    ln_kernel<<<4096, 256, 0, stream>>>(x1, ln2s, ln2b, hbuf);

    gemm_bt<4, 2><<<dim3(32, 32), 256, 0, stream>>>(hbuf, wt1, b1, nullptr, nullptr, nullptr,
                                                    hid, nullptr, nullptr, 4096, 4096, 1024);

    gemm_bt<2, 1><<<dim3(8, 64), 256, 0, stream>>>(hid, wt2, b2, nullptr, nullptr, x1,
                                                   (float*)d_out, nullptr, nullptr, 4096, 1024, 4096);
}

// Round 10
// 431.607 us; speedup vs baseline: 1.3633x; 1.0191x over previous
//
#include <hip/hip_runtime.h>
#include <hip/hip_bf16.h>
#include <stdint.h>

#define B_ 2
#define T_ 2048
#define C_ 1024
#define H_ 16
#define D_ 64
#define F_ 4096
#define M_ (B_*T_)

typedef unsigned short ushort_t;
typedef __attribute__((ext_vector_type(8))) short short8;
typedef __attribute__((ext_vector_type(4))) float f32x4;

__device__ __forceinline__ float bf2f(ushort_t u) {
    union { unsigned u; float f; } c; c.u = ((unsigned)u) << 16; return c.f;
}
__device__ __forceinline__ ushort_t f2bf(float f) {
    union { float f; unsigned u; } c; c.f = f;
    unsigned u = c.u;
    unsigned r = (u + 0x7FFFu + ((u >> 16) & 1u)) >> 16;
    return (ushort_t)r;
}

__device__ __forceinline__ float fexp2(float x) { return __builtin_amdgcn_exp2f(x); }

// async global->LDS, 16B per lane. LDS dest = wave-uniform base + lane*16.
__device__ __forceinline__ void async16(void* lds, const void* g) {
    __builtin_amdgcn_global_load_lds(
        (const __attribute__((address_space(1))) unsigned int*)(uintptr_t)g,
        (__attribute__((address_space(3))) unsigned int*)(uintptr_t)lds,
        16, 0, 0);
}

// ---------------------------------------------------------------------------
// Batched transpose+cast of all 6 weights: out_bf16[c][r] = in_f32[r][c]
// ---------------------------------------------------------------------------
__global__ __launch_bounds__(256) void transpose_all_k(
    const float* __restrict__ Wq, const float* __restrict__ Wk,
    const float* __restrict__ Wv, const float* __restrict__ Wo,
    const float* __restrict__ W1, const float* __restrict__ W2,
    ushort_t* __restrict__ oq, ushort_t* __restrict__ ok,
    ushort_t* __restrict__ ov, ushort_t* __restrict__ oo,
    ushort_t* __restrict__ o1, ushort_t* __restrict__ o2) {
    __shared__ ushort_t tile[32][33];
    int id = blockIdx.x;
    const float* in; ushort_t* out; int R, Cc, bx, by;
    if (id < 4096) {
        int w = id >> 10, loc = id & 1023;
        in  = w == 0 ? Wq : w == 1 ? Wk : w == 2 ? Wv : Wo;
        out = w == 0 ? oq : w == 1 ? ok : w == 2 ? ov : oo;
        R = 1024; Cc = 1024; bx = loc & 31; by = loc >> 5;
    } else if (id < 8192) {
        int loc = id - 4096; in = W1; out = o1; R = 1024; Cc = 4096;
        bx = loc & 127; by = loc >> 7;
    } else {
        int loc = id - 8192; in = W2; out = o2; R = 4096; Cc = 1024;
        bx = loc & 31; by = loc >> 5;
    }
    int tx = threadIdx.x, ty = threadIdx.y;
    int x = bx * 32 + tx;
    int y0 = by * 32;
#pragma unroll
    for (int i = 0; i < 32; i += 8)
        tile[ty + i][tx] = f2bf(in[(size_t)(y0 + ty + i) * Cc + x]);
    __syncthreads();
    int x2 = y0 + tx;
    int y2 = bx * 32;
#pragma unroll
    for (int i = 0; i < 32; i += 8)
        out[(size_t)(y2 + ty + i) * R + x2] = tile[tx][ty + i];
}

// ---------------------------------------------------------------------------
// LayerNorm: fp32 input row of 1024, fp32 scale/shift, bf16 output.
// ---------------------------------------------------------------------------
__global__ __launch_bounds__(256) void ln_kernel(const float* __restrict__ xin,
                                                 const float* __restrict__ scale_p,
                                                 const float* __restrict__ shift_p,
                                                 ushort_t* __restrict__ out) {
    int row = blockIdx.x, t = threadIdx.x;
    int wv = t >> 6, lane = t & 63;
    const float* xr = xin + (size_t)row * 1024 + t * 4;
    float4 v = *(const float4*)xr;
    float f[4] = {v.x, v.y, v.z, v.w};
    float s = f[0] + f[1] + f[2] + f[3];
    float q = f[0]*f[0] + f[1]*f[1] + f[2]*f[2] + f[3]*f[3];
#pragma unroll
    for (int off = 1; off < 64; off <<= 1) {
        s += __shfl_xor(s, off, 64);
        q += __shfl_xor(q, off, 64);
    }
    __shared__ float sh_s[4], sh_q[4];
    if (lane == 0) { sh_s[wv] = s; sh_q[wv] = q; }
    __syncthreads();
    float S = sh_s[0] + sh_s[1] + sh_s[2] + sh_s[3];
    float Q = sh_q[0] + sh_q[1] + sh_q[2] + sh_q[3];
    float mean = S * (1.0f / 1024.0f);
    float var = Q * (1.0f / 1024.0f) - mean * mean;
    float rstd = rsqrtf(var + 1e-5f);
    float4 scv = *(const float4*)(scale_p + t * 4);
    float4 shv = *(const float4*)(shift_p + t * 4);
    ushort4 o;
    o.x = f2bf((f[0] - mean) * rstd * scv.x + shv.x);
    o.y = f2bf((f[1] - mean) * rstd * scv.y + shv.y);
    o.z = f2bf((f[2] - mean) * rstd * scv.z + shv.z);
    o.w = f2bf((f[3] - mean) * rstd * scv.w + shv.w);
    *(ushort4*)(out + (size_t)row * 1024 + t * 4) = o;
}

// ---------------------------------------------------------------------------
// GEMM (m97 structure, async global->LDS staging):
// C[M,N] = A[M,K](bf16) @ Bt[N,K](bf16)^T + bias(f32)
// Tile (32*MT) x 128, BK=32, 4 waves 2x2.
// EPI: 1 = +f32 residual, f32 out; 2 = gelu, bf16 out
//      3 = QKV split: seg0/1 -> q,k row-major bf16; seg2 -> v transposed
// ---------------------------------------------------------------------------
template <int MT, int EPI>
__global__ __launch_bounds__(256) void gemm_bt(const ushort_t* __restrict__ A,
                                               const ushort_t* __restrict__ Bt,
                                               const float* __restrict__ b0,
                                               const float* __restrict__ b1,
                                               const float* __restrict__ b2,
                                               const float* __restrict__ res,
                                               void* __restrict__ out0,
                                               void* __restrict__ out1,
                                               void* __restrict__ out2,
                                               int M, int N, int K) {
    __shared__ ushort_t As[32 * MT * 32];
    __shared__ ushort_t Bs[128 * 32];
    const int t = threadIdx.x;
    const int wv = t >> 6, lane = t & 63, lo = lane & 15, hi = lane >> 4;
    const int wr = wv >> 1, wc = wv & 1;
    const int mb = blockIdx.y, nb = blockIdx.x;

    f32x4 acc[MT][4];
#pragma unroll
    for (int i = 0; i < MT; ++i)
#pragma unroll
        for (int j = 0; j < 4; ++j) acc[i][j] = (f32x4){0.f, 0.f, 0.f, 0.f};

    for (int k0 = 0; k0 < K; k0 += 32) {
#pragma unroll
        for (int i = 0; i < MT / 2; ++i) {
            int c = i * 256 + t;
            int row = c >> 2, kc = c & 3;
            async16((char*)As + (size_t)(i * 256 + wv * 64) * 16,
                    A + (size_t)(mb * 32 * MT + row) * K + k0 + kc * 8);
        }
#pragma unroll
        for (int i = 0; i < 2; ++i) {
            int c = i * 256 + t;
            int row = c >> 2, kc = c & 3;
            async16((char*)Bs + (size_t)(i * 256 + wv * 64) * 16,
                    Bt + (size_t)(nb * 128 + row) * K + k0 + kc * 8);
        }
        __syncthreads();

        short8 af[MT], bfr[4];
#pragma unroll
        for (int mi = 0; mi < MT; ++mi)
            af[mi] = *(const short8*)(As + (wr * 16 * MT + mi * 16 + lo) * 32 + hi * 8);
#pragma unroll
        for (int ni = 0; ni < 4; ++ni)
            bfr[ni] = *(const short8*)(Bs + (wc * 64 + ni * 16 + lo) * 32 + hi * 8);
#pragma unroll
        for (int mi = 0; mi < MT; ++mi)
#pragma unroll
            for (int ni = 0; ni < 4; ++ni)
                acc[mi][ni] = __builtin_amdgcn_mfma_f32_16x16x32_bf16(
                    af[mi], bfr[ni], acc[mi][ni], 0, 0, 0);
        __syncthreads();
    }

#pragma unroll
    for (int ni = 0; ni < 4; ++ni) {
        int n = nb * 128 + wc * 64 + ni * 16 + lo;
        float bn;
        ushort_t* obf = nullptr;
        int coln = n, seg = 0;
        if (EPI == 3) {
            seg = n >> 10; coln = n & 1023;
            bn = (seg == 0 ? b0 : seg == 1 ? b1 : b2)[coln];
            obf = (ushort_t*)(seg == 0 ? out0 : out1);
        } else {
            bn = b0[n];
        }
#pragma unroll
        for (int mi = 0; mi < MT; ++mi) {
            if (EPI == 3 && seg == 2) {
                int m0 = mb * 32 * MT + wr * 16 * MT + mi * 16 + 4 * hi;
                ushort4 pk;
                pk.x = f2bf(acc[mi][ni][0] + bn);
                pk.y = f2bf(acc[mi][ni][1] + bn);
                pk.z = f2bf(acc[mi][ni][2] + bn);
                pk.w = f2bf(acc[mi][ni][3] + bn);
                *(ushort4*)((ushort_t*)out2 + (size_t)coln * M + m0) = pk;
            } else {
#pragma unroll
                for (int r = 0; r < 4; ++r) {
                    int m = mb * 32 * MT + wr * 16 * MT + mi * 16 + 4 * hi + r;
                    float v = acc[mi][ni][r] + bn;
                    if (EPI == 1) {
                        size_t idx = (size_t)m * N + n;
                        ((float*)out0)[idx] = v + res[idx];
                    } else if (EPI == 2) {
                        v = 0.5f * v * (1.0f + erff(v * 0.70710678118654752f));
                        ((ushort_t*)out0)[(size_t)m * N + n] = f2bf(v);
                    } else {
                        obf[(size_t)m * 1024 + coln] = f2bf(v);
                    }
                }
            }
        }
    }
}

// ---------------------------------------------------------------------------
// Causal flash attention v3 (R9 green body) + complementary-pair block map:
// 1D grid of 512; ids c and c+256 get strips (q, 15-q), so every CU's two
// resident blocks sum to a uniform 34 tile-units (was up to 64).
// ---------------------------------------------------------------------------
__global__ __launch_bounds__(256) void attn_kernel(const ushort_t* __restrict__ q,
                                                   const ushort_t* __restrict__ k,
                                                   const ushort_t* __restrict__ vt,
                                                   ushort_t* __restrict__ ctx) {
    __shared__ ushort_t Ks[2][64 * 64];   // [buf][key][d], col-chunk swizzled
    __shared__ ushort_t VTs[2][64 * 64];  // [buf][d][key], col-chunk swizzled
    __shared__ ushort_t Ps[8][16 * 72];   // [wave*2+g][qrow][key], stride 72

    const int t = threadIdx.x;
    const int wv = t >> 6, lane = t & 63, lo = lane & 15, hi = lane >> 4;
    const int id = blockIdx.x;            // 512
    const int s = id >> 5;                // strip index 0..15
    const int qb = (s < 8) ? s : 23 - s;  // complementary pairing: s, s+8 -> q, 15-q
    const int bh = id & 31, b = bh >> 4, h = bh & 15;
    const int q0 = qb * 128;
    const size_t headoff = (size_t)h * 64;
    const size_t rowbase = (size_t)b * T_ * 1024;
    const ushort_t* vbase = vt + headoff * (size_t)M_ + (size_t)b * T_;

    short8 qf[2][2];
#pragma unroll
    for (int g = 0; g < 2; ++g) {
        const ushort_t* qp = q + rowbase + (size_t)(q0 + g * 64 + wv * 16 + lo) * 1024 + headoff;
        qf[g][0] = *(const short8*)(qp + hi * 8);
        qf[g][1] = *(const short8*)(qp + 32 + hi * 8);
    }

    float m_g[2], l_g[2];
    f32x4 o_acc[2][4];
#pragma unroll
    for (int g = 0; g < 2; ++g) {
        m_g[g] = -1e30f; l_g[g] = 0.f;
#pragma unroll
        for (int dt = 0; dt < 4; ++dt) o_acc[g][dt] = (f32x4){0.f, 0.f, 0.f, 0.f};
    }

    const int ktmax = 2 * qb + 1;
    const float SC = 0.18033688011112042f;  // 0.125 * log2(e)
    const f32x4 NEG4 = (f32x4){-1e30f, -1e30f, -1e30f, -1e30f};

    auto stage = [&](int bb, int kt) {
        const int k0s = kt * 64;
#pragma unroll
        for (int i = 0; i < 2; ++i) {
            int c = i * 256 + t;
            int row = c >> 3, c8 = c & 7;
            int gsw = c8 ^ (row & 7);
            async16((char*)&Ks[bb][0] + (size_t)(i * 256 + wv * 64) * 16,
                    k + rowbase + (size_t)(k0s + row) * 1024 + headoff + gsw * 8);
            async16((char*)&VTs[bb][0] + (size_t)(i * 256 + wv * 64) * 16,
                    vbase + (size_t)row * M_ + k0s + gsw * 8);
        }
    };

    auto softmax_g = [&](f32x4* sacc, int gi) {
        float mx = -1e30f;
#pragma unroll
        for (int kt16 = 0; kt16 < 4; ++kt16)
#pragma unroll
            for (int r = 0; r < 4; ++r) mx = fmaxf(mx, sacc[kt16][r]);
        mx = fmaxf(mx, __shfl_xor(mx, 16, 64));
        mx = fmaxf(mx, __shfl_xor(mx, 32, 64));
        float mnew = fmaxf(m_g[gi], mx);
        float alpha = fexp2(m_g[gi] - mnew);
        m_g[gi] = mnew;
        ushort_t* Pw = Ps[wv * 2 + gi];
        float rs = 0.f;
#pragma unroll
        for (int kt16 = 0; kt16 < 4; ++kt16) {
#pragma unroll
            for (int r = 0; r < 4; ++r) {
                float p = fexp2(sacc[kt16][r] - mnew);
                rs += p;
                Pw[lo * 72 + kt16 * 16 + 4 * hi + r] = f2bf(p);
            }
        }
        rs += __shfl_xor(rs, 16, 64);
        rs += __shfl_xor(rs, 32, 64);
        l_g[gi] = l_g[gi] * alpha + rs;
#pragma unroll
        for (int r = 0; r < 4; ++r) {
            float ab = __shfl(alpha, 4 * hi + r, 64);
#pragma unroll
            for (int dt = 0; dt < 4; ++dt) o_acc[gi][dt][r] *= ab;
        }
    };

    stage(0, 0);
    for (int kt = 0; kt <= ktmax; ++kt) {
        const int bb = kt & 1;
        const int k0 = kt * 64;
        __syncthreads();
        if (kt < ktmax) stage(bb ^ 1, kt + 1);

        short8 pf[2][2];
        int any_g[2];
#pragma unroll
        for (int g = 0; g < 2; ++g) {
            const int qg0 = q0 + g * 64 + wv * 16;
            const int diff = qg0 - k0;
            any_g[g] = (diff >= 0);
            if (!any_g[g]) continue;
            const int cmax = diff >= 48 ? 3 : (diff >> 4);

            f32x4 sacc[4];
#pragma unroll
            for (int kt16 = 0; kt16 < 4; ++kt16) {
                if (kt16 <= cmax) {
                    int row = kt16 * 16 + lo, sw = row & 7;
                    short8 kf0 = *(const short8*)(&Ks[bb][0] + row * 64 + (hi ^ sw) * 8);
                    short8 kf1 = *(const short8*)(&Ks[bb][0] + row * 64 + ((4 + hi) ^ sw) * 8);
                    f32x4 z = (f32x4){0.f, 0.f, 0.f, 0.f};
                    z = __builtin_amdgcn_mfma_f32_16x16x32_bf16(kf0, qf[g][0], z, 0, 0, 0);
                    z = __builtin_amdgcn_mfma_f32_16x16x32_bf16(kf1, qf[g][1], z, 0, 0, 0);
#pragma unroll
                    for (int r = 0; r < 4; ++r) sacc[kt16][r] = z[r] * SC;
                } else {
                    sacc[kt16] = NEG4;
                }
            }
            if (diff < 64) {  // diagonal subtile: element mask key > qrow
                const int qrow = diff + lo;
#pragma unroll
                for (int r = 0; r < 4; ++r) {
                    int key = cmax * 16 + 4 * hi + r;
                    if (key > qrow) sacc[cmax][r] = -1e30f;
                }
            }

            softmax_g(sacc, g);

            pf[g][0] = *(const short8*)(Ps[wv * 2 + g] + lo * 72 + hi * 8);
            pf[g][1] = *(const short8*)(Ps[wv * 2 + g] + lo * 72 + 32 + hi * 8);
        }

        // PV: V^T fragments shared across both groups
#pragma unroll
        for (int dt = 0; dt < 4; ++dt) {
            int row = dt * 16 + lo, sw = row & 7;
            short8 vf0 = *(const short8*)(&VTs[bb][0] + row * 64 + (hi ^ sw) * 8);
            short8 vf1 = *(const short8*)(&VTs[bb][0] + row * 64 + ((4 + hi) ^ sw) * 8);
#pragma unroll
            for (int g = 0; g < 2; ++g) {
                if (!any_g[g]) continue;
                o_acc[g][dt] = __builtin_amdgcn_mfma_f32_16x16x32_bf16(pf[g][0], vf0, o_acc[g][dt], 0, 0, 0);
                o_acc[g][dt] = __builtin_amdgcn_mfma_f32_16x16x32_bf16(pf[g][1], vf1, o_acc[g][dt], 0, 0, 0);
            }
        }
    }

#pragma unroll
    for (int g = 0; g < 2; ++g) {
#pragma unroll
        for (int r = 0; r < 4; ++r) {
            float lb = __shfl(l_g[g], 4 * hi + r, 64);
            float inv = 1.0f / lb;
            size_t row = rowbase + (size_t)(q0 + g * 64 + wv * 16 + 4 * hi + r) * 1024 + headoff;
#pragma unroll
            for (int dt = 0; dt < 4; ++dt)
                ctx[row + dt * 16 + lo] = f2bf(o_acc[g][dt][r] * inv);
        }
    }
}

// ---------------------------------------------------------------------------
extern "C" void kernel_launch(void* const* d_in, const int* in_sizes, int n_in,
                              void* d_out, int out_size, void* d_ws, size_t ws_size,
                              hipStream_t stream) {
    (void)in_sizes; (void)n_in; (void)out_size; (void)ws_size;
    const float* x    = (const float*)d_in[0];
    const float* Wq   = (const float*)d_in[1];
    const float* bq   = (const float*)d_in[2];
    const float* Wk   = (const float*)d_in[3];
    const float* bk   = (const float*)d_in[4];
    const float* Wv   = (const float*)d_in[5];
    const float* bv   = (const float*)d_in[6];
    const float* Wo   = (const float*)d_in[7];
    const float* bo   = (const float*)d_in[8];
    const float* W1   = (const float*)d_in[9];
    const float* b1   = (const float*)d_in[10];
    const float* W2   = (const float*)d_in[11];
    const float* b2   = (const float*)d_in[12];
    const float* ln1s = (const float*)d_in[13];
    const float* ln1b = (const float*)d_in[14];
    const float* ln2s = (const float*)d_in[15];
    const float* ln2b = (const float*)d_in[16];

    char* ws = (char*)d_ws;
    const size_t MB = 1024 * 1024;
    ushort_t* wqkv = (ushort_t*)(ws + 0 * MB);   // wtq|wtk|wtv contiguous [3072][1024]
    ushort_t* wtq  = (ushort_t*)(ws + 0 * MB);
    ushort_t* wtk  = (ushort_t*)(ws + 2 * MB);
    ushort_t* wtv  = (ushort_t*)(ws + 4 * MB);
    ushort_t* wto  = (ushort_t*)(ws + 6 * MB);
    ushort_t* wt1  = (ushort_t*)(ws + 8 * MB);   // 8MB (4096x1024)
    ushort_t* wt2  = (ushort_t*)(ws + 16 * MB);  // 8MB (1024x4096)
    ushort_t* hbuf = (ushort_t*)(ws + 24 * MB);  // 8MB
    ushort_t* qb_  = (ushort_t*)(ws + 32 * MB);  // 8MB
    ushort_t* kb_  = (ushort_t*)(ws + 40 * MB);  // 8MB
    ushort_t* ctx  = (ushort_t*)(ws + 56 * MB);  // 8MB
    ushort_t* hid  = (ushort_t*)(ws + 32 * MB);  // 32MB, reuses q/k/ctx post-attn
    float*    x1   = (float*)(ws + 64 * MB);     // 16MB fp32 (written after attn)
    ushort_t* vtb  = (ushort_t*)(ws + 64 * MB);  // 8MB [1024][4096], dead after attn

    transpose_all_k<<<12288, dim3(32, 8), 0, stream>>>(Wq, Wk, Wv, Wo, W1, W2,
                                                       wtq, wtk, wtv, wto, wt1, wt2);

    ln_kernel<<<4096, 256, 0, stream>>>(x, ln1s, ln1b, hbuf);

    // fused QKV; seg2 writes v^T directly into vtb [1024][4096]
    gemm_bt<4, 3><<<dim3(24, 32), 256, 0, stream>>>(hbuf, wqkv, bq, bk, bv, nullptr,
                                                    qb_, kb_, vtb, 4096, 3072, 1024);

    attn_kernel<<<512, 256, 0, stream>>>(qb_, kb_, vtb, ctx);

    gemm_bt<2, 1><<<dim3(8, 64), 256, 0, stream>>>(ctx, wto, bo, nullptr, nullptr, x,
                                                   x1, nullptr, nullptr, 4096, 1024, 1024);

    ln_kernel<<<4096, 256, 0, stream>>>(x1, ln2s, ln2b, hbuf);

    gemm_bt<4, 2><<<dim3(32, 32), 256, 0, stream>>>(hbuf, wt1, b1, nullptr, nullptr, nullptr,
                                                    hid, nullptr, nullptr, 4096, 4096, 1024);

    gemm_bt<2, 1><<<dim3(8, 64), 256, 0, stream>>>(hid, wt2, b2, nullptr, nullptr, x1,
                                                   (float*)d_out, nullptr, nullptr, 4096, 1024, 4096);
}